// Round 10
// baseline (1358.144 us; speedup 1.0000x reference)
//
#include <hip/hip_runtime.h>

typedef float f32x4 __attribute__((ext_vector_type(4)));
typedef short s16x8 __attribute__((ext_vector_type(8)));

#define ECAP 36864   // padded per-bucket edge capacity (mean 32768, +22 sigma)

__device__ __forceinline__ ushort f2bf(float f) {
  uint u = __builtin_bit_cast(uint, f);
  u += 0x7fffu + ((u >> 16) & 1u);
  return (ushort)(u >> 16);
}
__device__ __forceinline__ float bfu_lo(uint u) { return __builtin_bit_cast(float, u << 16); }
__device__ __forceinline__ float bfu_hi(uint u) { return __builtin_bit_cast(float, u & 0xffff0000u); }

// ---------------- reformat 8 weight matrices into MFMA B-fragment order ----------------
// Wf[m][(nt*4+ks)*64 + lane][i] = bf16( W_m[ks*32 + (lane>>4)*8 + i][nt*16 + (lane&15)] )
// also initializes bcur (bucket cursors)
__global__ void k_prepw(const float* __restrict__ Wp1, const float* __restrict__ Wp2,
                        const float* __restrict__ W1s, const float* __restrict__ W2s,
                        ushort* __restrict__ Wf, int* __restrict__ bcur, int nbk) {
  int t = blockIdx.x * blockDim.x + threadIdx.x;
  if (t <= nbk) bcur[t] = t * ECAP;
  if (t >= 8 * 2048) return;
  int m = t >> 11;
  int r = t & 2047;
  int lane = r & 63;
  int ksnt = r >> 6;
  int ks = ksnt & 3;
  int nt = ksnt >> 2;
  const float* src = (m == 0) ? Wp1 : (m == 1) ? Wp2
                     : (m < 5) ? (W1s + (size_t)(m - 2) * 16384)
                               : (W2s + (size_t)(m - 5) * 16384);
  ushort* dst = Wf + (size_t)m * 16384 + (size_t)r * 8;
  int c = nt * 16 + (lane & 15);
  int kbase = ks * 32 + (lane >> 4) * 8;
  for (int i = 0; i < 8; ++i) dst[i] = f2bf(src[(size_t)(kbase + i) * 128 + c]);
}

// ---------------- LDS-staged multi-split: partition edges into dst-range buckets ---------
#define PNBK 64
#define PCAP 80
#define PEPB 2048
__global__ __launch_bounds__(256)
void k_part(const int* __restrict__ src, const int* __restrict__ dst,
            int* __restrict__ bcur, uint2* __restrict__ ebuf, int E) {
  __shared__ uint2 stage[PNBK][PCAP];
  __shared__ int lcnt[PNBK];
  int tid = threadIdx.x;
  if (tid < PNBK) lcnt[tid] = 0;
  __syncthreads();
  int e0 = blockIdx.x * PEPB;
  for (int r = 0; r < PEPB / 256; ++r) {
    int e = e0 + r * 256 + tid;
    if (e < E) {
      int d = dst[e], s = src[e];
      int b = d >> 11;
      int pos = atomicAdd(&lcnt[b], 1);
      uint2 pr; pr.x = (uint)s; pr.y = (uint)d;
      if (pos < PCAP) {
        stage[b][pos] = pr;
      } else {  // overflow fallback (correct for any data)
        int p = atomicAdd(&bcur[b], 1);
        ebuf[p] = pr;
      }
    }
    if (r == 3 || r == PEPB / 256 - 1) {
      __syncthreads();
      if (tid < PNBK) {
        int c = lcnt[tid];
        if (c > PCAP) c = PCAP;
        if (c > 0) {
          int base = atomicAdd(&bcur[tid], c);
          for (int i = 0; i < c; ++i) ebuf[base + i] = stage[tid][i];
          lcnt[tid] = 0;
        }
      }
      __syncthreads();
    }
  }
}

// ---------------- per-bucket LDS counting sort ----------------
__global__ __launch_bounds__(1024)
void k_sort(const uint2* __restrict__ ebuf, const int* __restrict__ bcur,
            int* __restrict__ rowbeg, int* __restrict__ rowend,
            int* __restrict__ csr, int N) {
  __shared__ int lcnt[2048];
  __shared__ int loff[2048];
  __shared__ int wsum[16];
  const int b = blockIdx.x;
  const int tid = threadIdx.x;
  const int lane = tid & 63, w = tid >> 6;
  const int base_e = b * ECAP;
  const int node0 = b << 11;
  const int ecnt = bcur[b] - base_e;

  lcnt[tid] = 0; lcnt[tid + 1024] = 0;
  __syncthreads();
  for (int i = tid; i < ecnt; i += 1024) {
    int d = (int)ebuf[base_e + i].y;
    atomicAdd(&lcnt[d - node0], 1);
  }
  __syncthreads();
  int v0 = lcnt[2 * tid], v1 = lcnt[2 * tid + 1];
  int s = v0 + v1;
  for (int off = 1; off < 64; off <<= 1) {
    int t = __shfl_up(s, off);
    if (lane >= off) s += t;
  }
  if (lane == 63) wsum[w] = s;
  __syncthreads();
  if (w == 0 && lane < 16) {
    int x = wsum[lane];
    int sx = x;
    for (int off = 1; off < 16; off <<= 1) {
      int t = __shfl_up(sx, off);
      if (lane >= off) sx += t;
    }
    wsum[lane] = sx - x;
  }
  __syncthreads();
  int excl = wsum[w] + (s - v0 - v1);
  loff[2 * tid] = excl;
  loff[2 * tid + 1] = excl + v0;
  __syncthreads();
  for (int i = tid; i < 2048; i += 1024) {
    int g = node0 + i;
    if (g < N) {
      int rb = base_e + loff[i];
      rowbeg[g] = rb;
      rowend[g] = rb + lcnt[i];
    }
    lcnt[i] = 0;
  }
  __syncthreads();
  for (int i = tid; i < ecnt; i += 1024) {
    uint2 p = ebuf[base_e + i];
    int dloc = (int)p.y - node0;
    int pos = base_e + loff[dloc] + atomicAdd(&lcnt[dloc], 1);
    csr[pos] = (int)p.x;
  }
}

// ---------------- per-wave full MLP of one 16-row tile (in-place LDS) ----------------
// T layout: element (row, col) bf16 at byte (row*256 + col*2) ^ ((row&7)<<4)
__device__ __forceinline__ void mlp_tile(uint* T, int m0,
    const s16x8* __restrict__ wf1, const s16x8* __restrict__ wf2,
    const float* __restrict__ b1, const float* __restrict__ b2,
    ushort* __restrict__ Hout, const int* __restrict__ batch,
    float* __restrict__ pool, int col_off, int M, int lane) {
  const int row = lane & 15, hi = lane >> 4;
  f32x4 acc[8];
#pragma unroll
  for (int nt = 0; nt < 8; ++nt) acc[nt] = (f32x4){0.f, 0.f, 0.f, 0.f};
#pragma unroll
  for (int ks = 0; ks < 4; ++ks) {
    const s16x8 af = *(const s16x8*)(T + row * 64 + ((ks * 16 + hi * 4) ^ ((row & 7) << 2)));
#pragma unroll
    for (int nt = 0; nt < 8; ++nt)
      acc[nt] = __builtin_amdgcn_mfma_f32_16x16x32_bf16(af, wf1[(nt * 4 + ks) * 64 + lane], acc[nt], 0, 0, 0);
  }
  {
    ushort* Tb = (ushort*)T;
#pragma unroll
    for (int nt = 0; nt < 8; ++nt) {
      float bb = b1[nt * 16 + row];
      const int col = nt * 16 + row;
#pragma unroll
      for (int i = 0; i < 4; ++i) {
        int lr = hi * 4 + i;
        float v = fmaxf(acc[nt][i] + bb, 0.f);
        Tb[(lr * 128 + col) ^ ((lr & 7) << 3)] = f2bf(v);
      }
    }
  }
#pragma unroll
  for (int nt = 0; nt < 8; ++nt) acc[nt] = (f32x4){0.f, 0.f, 0.f, 0.f};
#pragma unroll
  for (int ks = 0; ks < 4; ++ks) {
    const s16x8 af = *(const s16x8*)(T + row * 64 + ((ks * 16 + hi * 4) ^ ((row & 7) << 2)));
#pragma unroll
    for (int nt = 0; nt < 8; ++nt)
      acc[nt] = __builtin_amdgcn_mfma_f32_16x16x32_bf16(af, wf2[(nt * 4 + ks) * 64 + lane], acc[nt], 0, 0, 0);
  }
  {
    const int r0 = m0 + hi * 4;
    const bool full = (m0 + 15 < M);
    const int gf = batch[m0 < M ? m0 : (M - 1)];
    const int gl = batch[(m0 + 15) < M ? (m0 + 15) : (M - 1)];
    if (full && gf == gl) {
#pragma unroll
      for (int nt = 0; nt < 8; ++nt) {
        const int col = nt * 16 + row;
        float bb = b2[col];
        float vs = 0.f;
#pragma unroll
        for (int i = 0; i < 4; ++i) {
          float v = acc[nt][i] + bb;
          Hout[(size_t)(r0 + i) * 128 + col] = f2bf(v);
          vs += v;
        }
        vs += __shfl_xor(vs, 16);
        vs += __shfl_xor(vs, 32);
        if (lane < 16) atomicAdd(&pool[(size_t)gf * 384 + col_off + nt * 16 + lane], vs);
      }
    } else {
#pragma unroll
      for (int nt = 0; nt < 8; ++nt) {
        const int col = nt * 16 + row;
        float bb = b2[col];
#pragma unroll
        for (int i = 0; i < 4; ++i) {
          const int rr = r0 + i;
          if (rr < M) {
            float v = acc[nt][i] + bb;
            Hout[(size_t)rr * 128 + col] = f2bf(v);
            int g = batch[rr];
            atomicAdd(&pool[(size_t)g * 384 + col_off + col], v);
          }
        }
      }
    }
  }
}

// ---------------- fused GIN layer: producer/consumer wave pipeline ----------------
// persistent blocks of 6 waves: waves 0-4 gather tile t into Tz[buf] (3-4 rows each);
// wave 5 runs the full MLP of tile t-G from Tz[buf^1]. One barrier per tile.
__global__ __launch_bounds__(384, 7)
void k_layer(const ushort* __restrict__ H, const int* __restrict__ rowbeg,
             const int* __restrict__ rowend, const int* __restrict__ csr,
             const ushort* __restrict__ Wf1, const ushort* __restrict__ Wf2,
             const float* __restrict__ b1, const float* __restrict__ b2,
             const float* __restrict__ eps, int layer,
             ushort* __restrict__ Hout, const int* __restrict__ batch,
             float* __restrict__ pool, int col_off, int M) {
  __shared__ uint Tz[2][1024];   // two 16x128 bf16 tiles, XOR-swizzled
  const int tid = threadIdx.x;
  const int w = tid >> 6, lane = tid & 63;
  const float e = 1.0f + eps[layer];
  const uint* h32 = (const uint*)H;
  const s16x8* wf1 = (const s16x8*)Wf1;
  const s16x8* wf2 = (const s16x8*)Wf2;
  const int ntiles = (M + 15) >> 4;

  int prev = -1;
  int buf = 0;
  for (int t = blockIdx.x; t < ntiles; t += gridDim.x) {
    if (w < 5) {
      // gather rows [w*16/5, (w+1)*16/5) of tile t
      const int rs = (w * 16) / 5;
      const int re = ((w + 1) * 16) / 5;
      uint* T = Tz[buf];
      for (int row = rs; row < re; ++row) {
        const int n = t * 16 + row;
        if (n < M) {
          uint u = h32[(size_t)n * 64 + lane];
          float a0 = bfu_lo(u) * e, a1 = bfu_hi(u) * e;
          int s0 = rowbeg[n], s1 = rowend[n];
          for (int base = s0; base < s1; base += 64) {
            int cnt = s1 - base;
            if (cnt > 64) cnt = 64;
            int idx = (lane < cnt) ? csr[base + lane] : 0;
            int j = 0;
            for (; j + 4 <= cnt; j += 4) {
              int i0 = __shfl(idx, j), i1 = __shfl(idx, j + 1);
              int i2 = __shfl(idx, j + 2), i3 = __shfl(idx, j + 3);
              uint u0 = h32[(size_t)i0 * 64 + lane];
              uint u1 = h32[(size_t)i1 * 64 + lane];
              uint u2 = h32[(size_t)i2 * 64 + lane];
              uint u3 = h32[(size_t)i3 * 64 + lane];
              a0 += bfu_lo(u0); a1 += bfu_hi(u0);
              a0 += bfu_lo(u1); a1 += bfu_hi(u1);
              a0 += bfu_lo(u2); a1 += bfu_hi(u2);
              a0 += bfu_lo(u3); a1 += bfu_hi(u3);
            }
            for (; j < cnt; ++j) {
              int si = __shfl(idx, j);
              uint uu = h32[(size_t)si * 64 + lane];
              a0 += bfu_lo(uu); a1 += bfu_hi(uu);
            }
          }
          T[row * 64 + (lane ^ ((row & 7) << 2))] = (uint)f2bf(a0) | ((uint)f2bf(a1) << 16);
        }
      }
    } else if (prev >= 0) {
      mlp_tile(Tz[buf ^ 1], prev * 16, wf1, wf2, b1, b2, Hout, batch, pool, col_off, M, lane);
    }
    __syncthreads();
    prev = t;
    buf ^= 1;
  }
  // drain: last gathered tile
  if (w == 5 && prev >= 0)
    mlp_tile(Tz[buf ^ 1], prev * 16, wf1, wf2, b1, b2, Hout, batch, pool, col_off, M, lane);
}

// ---------------- fused pre-MLP: h = relu(relu(x@Wp1+bp1)@Wp2+bp2), x f32 ----------------
__global__ __launch_bounds__(256, 4)
void k_mlp2(const float* __restrict__ X, const ushort* __restrict__ Wf1,
            const ushort* __restrict__ Wf2, const float* __restrict__ b1,
            const float* __restrict__ b2, ushort* __restrict__ Hout, int M) {
  __shared__ uint lt[4][1024];
  const int lane = threadIdx.x & 63;
  const int wid = threadIdx.x >> 6;
  uint* T = lt[wid];
  const int m0 = blockIdx.x * 64 + wid * 16;
  if (m0 >= M) return;
  const int row = lane & 15, hi = lane >> 4;

  f32x4 acc[8];
#pragma unroll
  for (int nt = 0; nt < 8; ++nt) acc[nt] = (f32x4){0.f, 0.f, 0.f, 0.f};
  {
    const float* xrow = X + (size_t)(m0 + row) * 128;
    const s16x8* wf = (const s16x8*)Wf1;
#pragma unroll
    for (int ks = 0; ks < 4; ++ks) {
      float4 xa = *(const float4*)&xrow[ks * 32 + hi * 8];
      float4 xb = *(const float4*)&xrow[ks * 32 + hi * 8 + 4];
      s16x8 af;
      af[0] = (short)f2bf(xa.x); af[1] = (short)f2bf(xa.y);
      af[2] = (short)f2bf(xa.z); af[3] = (short)f2bf(xa.w);
      af[4] = (short)f2bf(xb.x); af[5] = (short)f2bf(xb.y);
      af[6] = (short)f2bf(xb.z); af[7] = (short)f2bf(xb.w);
#pragma unroll
      for (int nt = 0; nt < 8; ++nt)
        acc[nt] = __builtin_amdgcn_mfma_f32_16x16x32_bf16(af, wf[(nt * 4 + ks) * 64 + lane], acc[nt], 0, 0, 0);
    }
  }
  {
    ushort* Tb = (ushort*)T;
    const int r0l = hi * 4;
#pragma unroll
    for (int nt = 0; nt < 8; ++nt) {
      float bb = b1[nt * 16 + row];
      const int col = nt * 16 + row;
#pragma unroll
      for (int i = 0; i < 4; ++i) {
        int lr = r0l + i;
        float v = fmaxf(acc[nt][i] + bb, 0.f);
        Tb[(lr * 128 + col) ^ ((lr & 7) << 3)] = f2bf(v);
      }
    }
  }
#pragma unroll
  for (int nt = 0; nt < 8; ++nt) acc[nt] = (f32x4){0.f, 0.f, 0.f, 0.f};
  {
#pragma unroll
    for (int ks = 0; ks < 4; ++ks) {
      int ub = row * 64 + ((ks * 16 + hi * 4) ^ ((row & 7) << 2));
      s16x8 af = *(const s16x8*)(T + ub);
#pragma unroll
      for (int nt = 0; nt < 8; ++nt)
        acc[nt] = __builtin_amdgcn_mfma_f32_16x16x32_bf16(af, ((const s16x8*)Wf2)[(nt * 4 + ks) * 64 + lane], acc[nt], 0, 0, 0);
    }
  }
  {
    const int r0 = m0 + hi * 4;
#pragma unroll
    for (int nt = 0; nt < 8; ++nt) {
      const int col = nt * 16 + row;
      float bb = b2[col];
#pragma unroll
      for (int i = 0; i < 4; ++i) {
        float v = fmaxf(acc[nt][i] + bb, 0.f);
        Hout[(size_t)(r0 + i) * 128 + col] = f2bf(v);
      }
    }
  }
}

extern "C" void kernel_launch(void* const* d_in, const int* in_sizes, int n_in,
                              void* d_out, int out_size, void* d_ws, size_t ws_size,
                              hipStream_t stream) {
  const float* x    = (const float*)d_in[0];
  const int*   ei   = (const int*)d_in[1];
  const int*   batch= (const int*)d_in[2];
  const float* Wp1  = (const float*)d_in[3];
  const float* bp1  = (const float*)d_in[4];
  const float* Wp2  = (const float*)d_in[5];
  const float* bp2  = (const float*)d_in[6];
  const float* W1s  = (const float*)d_in[7];
  const float* b1s  = (const float*)d_in[8];
  const float* W2s  = (const float*)d_in[9];
  const float* b2s  = (const float*)d_in[10];
  const float* eps  = (const float*)d_in[11];

  const int N = in_sizes[0] / 128;
  const int E = in_sizes[1] / 2;
  float* out = (float*)d_out;
  const int nbk = (N + 2047) >> 11;

  char* ws = (char*)d_ws;
  size_t off = 0;
  auto alloc = [&](size_t bytes) -> void* {
    void* p = ws + off;
    off += (bytes + 255) & ~(size_t)255;
    return p;
  };
  ushort* bufA  = (ushort*)alloc((size_t)N * 128 * 2);
  ushort* bufB  = (ushort*)alloc((size_t)N * 128 * 2);
  ushort* Wf    = (ushort*)alloc((size_t)8 * 16384 * 2);
  int* rowbeg   = (int*)alloc((size_t)N * 4);
  int* rowend   = (int*)alloc((size_t)N * 4);
  int* csr      = (int*)alloc((size_t)nbk * ECAP * 4);
  uint2* ebuf   = (uint2*)alloc((size_t)nbk * ECAP * 8);
  int* bcur     = (int*)alloc((size_t)(nbk + 1) * 4);
  (void)ws_size; (void)n_in;

  hipMemsetAsync(out, 0, (size_t)out_size * 4, stream);

  k_prepw<<<64, 256, 0, stream>>>(Wp1, Wp2, W1s, W2s, Wf, bcur, nbk);
  k_part<<<(E + PEPB - 1) / PEPB, 256, 0, stream>>>(ei, ei + E, bcur, ebuf, E);
  k_sort<<<nbk, 1024, 0, stream>>>(ebuf, bcur, rowbeg, rowend, csr, N);

  const int ngrid = (N + 63) / 64;
  k_mlp2<<<ngrid, 256, 0, stream>>>(x, Wf + 0 * 16384, Wf + 1 * 16384, bp1, bp2, bufA, N);

  const int ntiles = (N + 15) / 16;
  int lgrid = 256 * 5;                 // 5 persistent blocks per CU
  if (lgrid > ntiles) lgrid = ntiles;
  ushort* hin = bufA;
  ushort* hout = bufB;
  for (int L = 0; L < 3; ++L) {
    k_layer<<<lgrid, 384, 0, stream>>>(hin, rowbeg, rowend, csr,
                                       Wf + (2 + L) * 16384, Wf + (5 + L) * 16384,
                                       b1s + (size_t)L * 128, b2s + (size_t)L * 128,
                                       eps, L, hout, batch, out, L * 128, N);
    ushort* tmp = hin; hin = hout; hout = tmp;
  }
}

// Round 11
// 399.573 us; speedup vs baseline: 3.3990x; 3.3990x over previous
//
#include <hip/hip_runtime.h>

typedef float f32x4 __attribute__((ext_vector_type(4)));
typedef short s16x8 __attribute__((ext_vector_type(8)));

#define ECAP 36864   // padded per-bucket edge capacity (mean 32768, +22 sigma)

__device__ __forceinline__ ushort f2bf(float f) {
  uint u = __builtin_bit_cast(uint, f);
  u += 0x7fffu + ((u >> 16) & 1u);
  return (ushort)(u >> 16);
}
__device__ __forceinline__ float bfu_lo(uint u) { return __builtin_bit_cast(float, u << 16); }
__device__ __forceinline__ float bfu_hi(uint u) { return __builtin_bit_cast(float, u & 0xffff0000u); }

// ---------------- reformat 8 weight matrices into MFMA B-fragment order ----------------
// Wf[m][(nt*4+ks)*64 + lane][i] = bf16( W_m[ks*32 + (lane>>4)*8 + i][nt*16 + (lane&15)] )
// also initializes bcur (bucket cursors)
__global__ void k_prepw(const float* __restrict__ Wp1, const float* __restrict__ Wp2,
                        const float* __restrict__ W1s, const float* __restrict__ W2s,
                        ushort* __restrict__ Wf, int* __restrict__ bcur, int nbk) {
  int t = blockIdx.x * blockDim.x + threadIdx.x;
  if (t <= nbk) bcur[t] = t * ECAP;
  if (t >= 8 * 2048) return;
  int m = t >> 11;
  int r = t & 2047;
  int lane = r & 63;
  int ksnt = r >> 6;
  int ks = ksnt & 3;
  int nt = ksnt >> 2;
  const float* src = (m == 0) ? Wp1 : (m == 1) ? Wp2
                     : (m < 5) ? (W1s + (size_t)(m - 2) * 16384)
                               : (W2s + (size_t)(m - 5) * 16384);
  ushort* dst = Wf + (size_t)m * 16384 + (size_t)r * 8;
  int c = nt * 16 + (lane & 15);
  int kbase = ks * 32 + (lane >> 4) * 8;
  for (int i = 0; i < 8; ++i) dst[i] = f2bf(src[(size_t)(kbase + i) * 128 + c]);
}

// ---------------- LDS-staged multi-split: partition edges into dst-range buckets ---------
#define PNBK 64
#define PCAP 80
#define PEPB 2048
__global__ __launch_bounds__(256)
void k_part(const int* __restrict__ src, const int* __restrict__ dst,
            int* __restrict__ bcur, uint2* __restrict__ ebuf, int E) {
  __shared__ uint2 stage[PNBK][PCAP];
  __shared__ int lcnt[PNBK];
  int tid = threadIdx.x;
  if (tid < PNBK) lcnt[tid] = 0;
  __syncthreads();
  int e0 = blockIdx.x * PEPB;
  for (int r = 0; r < PEPB / 256; ++r) {
    int e = e0 + r * 256 + tid;
    if (e < E) {
      int d = dst[e], s = src[e];
      int b = d >> 11;
      int pos = atomicAdd(&lcnt[b], 1);
      uint2 pr; pr.x = (uint)s; pr.y = (uint)d;
      if (pos < PCAP) {
        stage[b][pos] = pr;
      } else {  // overflow fallback (correct for any data)
        int p = atomicAdd(&bcur[b], 1);
        ebuf[p] = pr;
      }
    }
    if (r == 3 || r == PEPB / 256 - 1) {
      __syncthreads();
      if (tid < PNBK) {
        int c = lcnt[tid];
        if (c > PCAP) c = PCAP;
        if (c > 0) {
          int base = atomicAdd(&bcur[tid], c);
          for (int i = 0; i < c; ++i) ebuf[base + i] = stage[tid][i];
          lcnt[tid] = 0;
        }
      }
      __syncthreads();
    }
  }
}

// ---------------- per-bucket LDS counting sort ----------------
__global__ __launch_bounds__(1024)
void k_sort(const uint2* __restrict__ ebuf, const int* __restrict__ bcur,
            int* __restrict__ rowbeg, int* __restrict__ rowend,
            int* __restrict__ csr, int N) {
  __shared__ int lcnt[2048];
  __shared__ int loff[2048];
  __shared__ int wsum[16];
  const int b = blockIdx.x;
  const int tid = threadIdx.x;
  const int lane = tid & 63, w = tid >> 6;
  const int base_e = b * ECAP;
  const int node0 = b << 11;
  const int ecnt = bcur[b] - base_e;

  lcnt[tid] = 0; lcnt[tid + 1024] = 0;
  __syncthreads();
  for (int i = tid; i < ecnt; i += 1024) {
    int d = (int)ebuf[base_e + i].y;
    atomicAdd(&lcnt[d - node0], 1);
  }
  __syncthreads();
  int v0 = lcnt[2 * tid], v1 = lcnt[2 * tid + 1];
  int s = v0 + v1;
  for (int off = 1; off < 64; off <<= 1) {
    int t = __shfl_up(s, off);
    if (lane >= off) s += t;
  }
  if (lane == 63) wsum[w] = s;
  __syncthreads();
  if (w == 0 && lane < 16) {
    int x = wsum[lane];
    int sx = x;
    for (int off = 1; off < 16; off <<= 1) {
      int t = __shfl_up(sx, off);
      if (lane >= off) sx += t;
    }
    wsum[lane] = sx - x;
  }
  __syncthreads();
  int excl = wsum[w] + (s - v0 - v1);
  loff[2 * tid] = excl;
  loff[2 * tid + 1] = excl + v0;
  __syncthreads();
  for (int i = tid; i < 2048; i += 1024) {
    int g = node0 + i;
    if (g < N) {
      int rb = base_e + loff[i];
      rowbeg[g] = rb;
      rowend[g] = rb + lcnt[i];
    }
    lcnt[i] = 0;
  }
  __syncthreads();
  for (int i = tid; i < ecnt; i += 1024) {
    uint2 p = ebuf[base_e + i];
    int dloc = (int)p.y - node0;
    int pos = base_e + loff[dloc] + atomicAdd(&lcnt[dloc], 1);
    csr[pos] = (int)p.x;
  }
}

// ---------------- fused GIN layer: 16-row tile, 4 waves, half-row gathers ----------------
// gather: wave w gathers column-half (w>>1) of rows (w&1)*8 .. +7.
//   Lanes form 2x32: sub = lane>>5 picks one of 2 neighbors per load, l32 = uint col.
//   Each 256B load instruction covers 2 neighbor half-rows (128 B = 1 L2 line each).
// MLP: wave w computes nt chunks {2w, 2w+1} for all 16 rows (identical to R9).
__global__ __launch_bounds__(256, 8)
void k_layer(const ushort* __restrict__ H, const int* __restrict__ rowbeg,
             const int* __restrict__ rowend, const int* __restrict__ csr,
             const ushort* __restrict__ Wf1, const ushort* __restrict__ Wf2,
             const float* __restrict__ b1, const float* __restrict__ b2,
             const float* __restrict__ eps, int layer,
             ushort* __restrict__ Hout, const int* __restrict__ batch,
             float* __restrict__ pool, int col_off, int M) {
  __shared__ uint Tz[1024];   // 16 rows x 64 uints (bf16x2), XOR-swizzled
  __shared__ uint Tt[1024];
  const int tid = threadIdx.x;
  const int w = tid >> 6, lane = tid & 63;
  const int m0 = blockIdx.x * 16;
  const float e = 1.0f + eps[layer];
  const uint* h32 = (const uint*)H;

  // ---- phase A: gather z half-rows (8 per wave) ----
  {
    const int sub = lane >> 5, l32 = lane & 31;
    const int half = w >> 1;
    const int hoff = half * 32 + l32;          // uint offset within a 64-uint row
    const int rbase = (w & 1) << 3;
    for (int r = 0; r < 8; ++r) {
      const int row = rbase + r;
      const int n = m0 + row;
      if (n < M) {
        uint us = (sub == 0) ? h32[(size_t)n * 64 + hoff] : 0u;
        float a0 = bfu_lo(us) * e, a1 = bfu_hi(us) * e;
        int s0 = rowbeg[n], s1 = rowend[n];
        for (int base = s0; base < s1; base += 64) {
          int cnt = s1 - base;
          if (cnt > 64) cnt = 64;
          int idx = (lane < cnt) ? csr[base + lane] : 0;
          int j = 0;
          for (; j + 8 <= cnt; j += 8) {
            int i0 = __shfl(idx, j + sub);
            int i1 = __shfl(idx, j + 2 + sub);
            int i2 = __shfl(idx, j + 4 + sub);
            int i3 = __shfl(idx, j + 6 + sub);
            uint u0 = h32[(size_t)i0 * 64 + hoff];
            uint u1 = h32[(size_t)i1 * 64 + hoff];
            uint u2 = h32[(size_t)i2 * 64 + hoff];
            uint u3 = h32[(size_t)i3 * 64 + hoff];
            a0 += bfu_lo(u0); a1 += bfu_hi(u0);
            a0 += bfu_lo(u1); a1 += bfu_hi(u1);
            a0 += bfu_lo(u2); a1 += bfu_hi(u2);
            a0 += bfu_lo(u3); a1 += bfu_hi(u3);
          }
          for (; j + 2 <= cnt; j += 2) {
            int si = __shfl(idx, j + sub);
            uint uu = h32[(size_t)si * 64 + hoff];
            a0 += bfu_lo(uu); a1 += bfu_hi(uu);
          }
          if (j < cnt) {
            int si = __shfl(idx, j);
            if (sub == 0) {
              uint uu = h32[(size_t)si * 64 + hoff];
              a0 += bfu_lo(uu); a1 += bfu_hi(uu);
            }
          }
        }
        a0 += __shfl_xor(a0, 32);
        a1 += __shfl_xor(a1, 32);
        if (sub == 0)
          Tz[row * 64 + (hoff ^ ((row & 7) << 2))] = (uint)f2bf(a0) | ((uint)f2bf(a1) << 16);
      }
    }
  }
  __syncthreads();

  // ---- phase B: GEMM1 (read Tz) -> relu -> Tt ----
  const int row16 = lane & 15, hi = lane >> 4;
  const int c2 = w << 1;
  const s16x8* wf1 = (const s16x8*)Wf1;
  f32x4 acc0 = (f32x4){0.f, 0.f, 0.f, 0.f};
  f32x4 acc1 = (f32x4){0.f, 0.f, 0.f, 0.f};
#pragma unroll
  for (int ks = 0; ks < 4; ++ks) {
    const s16x8 af = *(const s16x8*)(Tz + row16 * 64 + ((ks * 16 + hi * 4) ^ ((row16 & 7) << 2)));
    acc0 = __builtin_amdgcn_mfma_f32_16x16x32_bf16(af, wf1[((c2 + 0) * 4 + ks) * 64 + lane], acc0, 0, 0, 0);
    acc1 = __builtin_amdgcn_mfma_f32_16x16x32_bf16(af, wf1[((c2 + 1) * 4 + ks) * 64 + lane], acc1, 0, 0, 0);
  }
  {
    ushort* Tb = (ushort*)Tt;
    const float bb0 = b1[(c2 + 0) * 16 + row16];
    const float bb1 = b1[(c2 + 1) * 16 + row16];
#pragma unroll
    for (int i = 0; i < 4; ++i) {
      const int rr = hi * 4 + i;
      Tb[(rr * 128 + (c2 + 0) * 16 + row16) ^ ((rr & 7) << 3)] = f2bf(fmaxf(acc0[i] + bb0, 0.f));
      Tb[(rr * 128 + (c2 + 1) * 16 + row16) ^ ((rr & 7) << 3)] = f2bf(fmaxf(acc1[i] + bb1, 0.f));
    }
  }
  __syncthreads();

  // ---- phase C: GEMM2 (read Tt) + write + pool ----
  const s16x8* wf2 = (const s16x8*)Wf2;
  f32x4 ac0 = (f32x4){0.f, 0.f, 0.f, 0.f};
  f32x4 ac1 = (f32x4){0.f, 0.f, 0.f, 0.f};
#pragma unroll
  for (int ks = 0; ks < 4; ++ks) {
    const s16x8 af = *(const s16x8*)(Tt + row16 * 64 + ((ks * 16 + hi * 4) ^ ((row16 & 7) << 2)));
    ac0 = __builtin_amdgcn_mfma_f32_16x16x32_bf16(af, wf2[((c2 + 0) * 4 + ks) * 64 + lane], ac0, 0, 0, 0);
    ac1 = __builtin_amdgcn_mfma_f32_16x16x32_bf16(af, wf2[((c2 + 1) * 4 + ks) * 64 + lane], ac1, 0, 0, 0);
  }
  {
    const int r0 = m0 + hi * 4;
    const int col0 = (c2 + 0) * 16 + row16, col1 = (c2 + 1) * 16 + row16;
    const float bb0 = b2[col0], bb1 = b2[col1];
    const bool full = (m0 + 15 < M);
    const int gf = batch[m0 < M ? m0 : (M - 1)];
    const int gl = batch[(m0 + 15) < M ? (m0 + 15) : (M - 1)];
    if (full && gf == gl) {
      float vs0 = 0.f, vs1 = 0.f;
#pragma unroll
      for (int i = 0; i < 4; ++i) {
        float v0 = ac0[i] + bb0, v1 = ac1[i] + bb1;
        Hout[(size_t)(r0 + i) * 128 + col0] = f2bf(v0);
        Hout[(size_t)(r0 + i) * 128 + col1] = f2bf(v1);
        vs0 += v0; vs1 += v1;
      }
      vs0 += __shfl_xor(vs0, 16); vs0 += __shfl_xor(vs0, 32);
      vs1 += __shfl_xor(vs1, 16); vs1 += __shfl_xor(vs1, 32);
      if (lane < 16) {
        atomicAdd(&pool[(size_t)gf * 384 + col_off + (c2 + 0) * 16 + lane], vs0);
        atomicAdd(&pool[(size_t)gf * 384 + col_off + (c2 + 1) * 16 + lane], vs1);
      }
    } else {
#pragma unroll
      for (int i = 0; i < 4; ++i) {
        const int rr = r0 + i;
        if (rr < M) {
          float v0 = ac0[i] + bb0, v1 = ac1[i] + bb1;
          Hout[(size_t)rr * 128 + col0] = f2bf(v0);
          Hout[(size_t)rr * 128 + col1] = f2bf(v1);
          int g = batch[rr];
          atomicAdd(&pool[(size_t)g * 384 + col_off + col0], v0);
          atomicAdd(&pool[(size_t)g * 384 + col_off + col1], v1);
        }
      }
    }
  }
}

// ---------------- fused pre-MLP: h = relu(relu(x@Wp1+bp1)@Wp2+bp2), x f32 ----------------
__global__ __launch_bounds__(256, 4)
void k_mlp2(const float* __restrict__ X, const ushort* __restrict__ Wf1,
            const ushort* __restrict__ Wf2, const float* __restrict__ b1,
            const float* __restrict__ b2, ushort* __restrict__ Hout, int M) {
  __shared__ uint lt[4][1024];
  const int lane = threadIdx.x & 63;
  const int wid = threadIdx.x >> 6;
  uint* T = lt[wid];
  const int m0 = blockIdx.x * 64 + wid * 16;
  if (m0 >= M) return;
  const int row = lane & 15, hi = lane >> 4;

  f32x4 acc[8];
#pragma unroll
  for (int nt = 0; nt < 8; ++nt) acc[nt] = (f32x4){0.f, 0.f, 0.f, 0.f};
  {
    const float* xrow = X + (size_t)(m0 + row) * 128;
    const s16x8* wf = (const s16x8*)Wf1;
#pragma unroll
    for (int ks = 0; ks < 4; ++ks) {
      float4 xa = *(const float4*)&xrow[ks * 32 + hi * 8];
      float4 xb = *(const float4*)&xrow[ks * 32 + hi * 8 + 4];
      s16x8 af;
      af[0] = (short)f2bf(xa.x); af[1] = (short)f2bf(xa.y);
      af[2] = (short)f2bf(xa.z); af[3] = (short)f2bf(xa.w);
      af[4] = (short)f2bf(xb.x); af[5] = (short)f2bf(xb.y);
      af[6] = (short)f2bf(xb.z); af[7] = (short)f2bf(xb.w);
#pragma unroll
      for (int nt = 0; nt < 8; ++nt)
        acc[nt] = __builtin_amdgcn_mfma_f32_16x16x32_bf16(af, wf[(nt * 4 + ks) * 64 + lane], acc[nt], 0, 0, 0);
    }
  }
  {
    ushort* Tb = (ushort*)T;
    const int r0l = hi * 4;
#pragma unroll
    for (int nt = 0; nt < 8; ++nt) {
      float bb = b1[nt * 16 + row];
      const int col = nt * 16 + row;
#pragma unroll
      for (int i = 0; i < 4; ++i) {
        int lr = r0l + i;
        float v = fmaxf(acc[nt][i] + bb, 0.f);
        Tb[(lr * 128 + col) ^ ((lr & 7) << 3)] = f2bf(v);
      }
    }
  }
#pragma unroll
  for (int nt = 0; nt < 8; ++nt) acc[nt] = (f32x4){0.f, 0.f, 0.f, 0.f};
  {
#pragma unroll
    for (int ks = 0; ks < 4; ++ks) {
      int ub = row * 64 + ((ks * 16 + hi * 4) ^ ((row & 7) << 2));
      s16x8 af = *(const s16x8*)(T + ub);
#pragma unroll
      for (int nt = 0; nt < 8; ++nt)
        acc[nt] = __builtin_amdgcn_mfma_f32_16x16x32_bf16(af, ((const s16x8*)Wf2)[(nt * 4 + ks) * 64 + lane], acc[nt], 0, 0, 0);
    }
  }
  {
    const int r0 = m0 + hi * 4;
#pragma unroll
    for (int nt = 0; nt < 8; ++nt) {
      const int col = nt * 16 + row;
      float bb = b2[col];
#pragma unroll
      for (int i = 0; i < 4; ++i) {
        float v = fmaxf(acc[nt][i] + bb, 0.f);
        Hout[(size_t)(r0 + i) * 128 + col] = f2bf(v);
      }
    }
  }
}

extern "C" void kernel_launch(void* const* d_in, const int* in_sizes, int n_in,
                              void* d_out, int out_size, void* d_ws, size_t ws_size,
                              hipStream_t stream) {
  const float* x    = (const float*)d_in[0];
  const int*   ei   = (const int*)d_in[1];
  const int*   batch= (const int*)d_in[2];
  const float* Wp1  = (const float*)d_in[3];
  const float* bp1  = (const float*)d_in[4];
  const float* Wp2  = (const float*)d_in[5];
  const float* bp2  = (const float*)d_in[6];
  const float* W1s  = (const float*)d_in[7];
  const float* b1s  = (const float*)d_in[8];
  const float* W2s  = (const float*)d_in[9];
  const float* b2s  = (const float*)d_in[10];
  const float* eps  = (const float*)d_in[11];

  const int N = in_sizes[0] / 128;
  const int E = in_sizes[1] / 2;
  float* out = (float*)d_out;
  const int nbk = (N + 2047) >> 11;

  char* ws = (char*)d_ws;
  size_t off = 0;
  auto alloc = [&](size_t bytes) -> void* {
    void* p = ws + off;
    off += (bytes + 255) & ~(size_t)255;
    return p;
  };
  ushort* bufA  = (ushort*)alloc((size_t)N * 128 * 2);
  ushort* bufB  = (ushort*)alloc((size_t)N * 128 * 2);
  ushort* Wf    = (ushort*)alloc((size_t)8 * 16384 * 2);
  int* rowbeg   = (int*)alloc((size_t)N * 4);
  int* rowend   = (int*)alloc((size_t)N * 4);
  int* csr      = (int*)alloc((size_t)nbk * ECAP * 4);
  uint2* ebuf   = (uint2*)alloc((size_t)nbk * ECAP * 8);
  int* bcur     = (int*)alloc((size_t)(nbk + 1) * 4);
  (void)ws_size; (void)n_in;

  hipMemsetAsync(out, 0, (size_t)out_size * 4, stream);

  k_prepw<<<64, 256, 0, stream>>>(Wp1, Wp2, W1s, W2s, Wf, bcur, nbk);
  k_part<<<(E + PEPB - 1) / PEPB, 256, 0, stream>>>(ei, ei + E, bcur, ebuf, E);
  k_sort<<<nbk, 1024, 0, stream>>>(ebuf, bcur, rowbeg, rowend, csr, N);

  const int ngrid = (N + 63) / 64;
  k_mlp2<<<ngrid, 256, 0, stream>>>(x, Wf + 0 * 16384, Wf + 1 * 16384, bp1, bp2, bufA, N);

  const int lgrid = (N + 15) / 16;
  ushort* hin = bufA;
  ushort* hout = bufB;
  for (int L = 0; L < 3; ++L) {
    k_layer<<<lgrid, 256, 0, stream>>>(hin, rowbeg, rowend, csr,
                                       Wf + (2 + L) * 16384, Wf + (5 + L) * 16384,
                                       b1s + (size_t)L * 128, b2s + (size_t)L * 128,
                                       eps, L, hout, batch, out, L * 128, N);
    ushort* tmp = hin; hin = hout; hout = tmp;
  }
}

// Round 12
// 351.377 us; speedup vs baseline: 3.8652x; 1.1372x over previous
//
#include <hip/hip_runtime.h>

typedef float f32x4 __attribute__((ext_vector_type(4)));
typedef short s16x8 __attribute__((ext_vector_type(8)));

#define ECAP 36864   // padded per-bucket edge capacity (mean 32768, +22 sigma)

__device__ __forceinline__ ushort f2bf(float f) {
  uint u = __builtin_bit_cast(uint, f);
  u += 0x7fffu + ((u >> 16) & 1u);
  return (ushort)(u >> 16);
}
__device__ __forceinline__ float bfu_lo(uint u) { return __builtin_bit_cast(float, u << 16); }
__device__ __forceinline__ float bfu_hi(uint u) { return __builtin_bit_cast(float, u & 0xffff0000u); }

// ---------------- reformat 8 weight matrices into MFMA B-fragment order ----------------
// Wf[m][(nt*4+ks)*64 + lane][i] = bf16( W_m[ks*32 + (lane>>4)*8 + i][nt*16 + (lane&15)] )
// also initializes bcur (bucket cursors) and zeroes the pool output
__global__ void k_prepw(const float* __restrict__ Wp1, const float* __restrict__ Wp2,
                        const float* __restrict__ W1s, const float* __restrict__ W2s,
                        ushort* __restrict__ Wf, int* __restrict__ bcur, int nbk,
                        float* __restrict__ out, int out_size) {
  int t = blockIdx.x * blockDim.x + threadIdx.x;
  if (t <= nbk) bcur[t] = t * ECAP;
  for (int i = t; i < out_size; i += 16384) out[i] = 0.f;
  if (t >= 8 * 2048) return;
  int m = t >> 11;
  int r = t & 2047;
  int lane = r & 63;
  int ksnt = r >> 6;
  int ks = ksnt & 3;
  int nt = ksnt >> 2;
  const float* src = (m == 0) ? Wp1 : (m == 1) ? Wp2
                     : (m < 5) ? (W1s + (size_t)(m - 2) * 16384)
                               : (W2s + (size_t)(m - 5) * 16384);
  ushort* dst = Wf + (size_t)m * 16384 + (size_t)r * 8;
  int c = nt * 16 + (lane & 15);
  int kbase = ks * 32 + (lane >> 4) * 8;
  for (int i = 0; i < 8; ++i) dst[i] = f2bf(src[(size_t)(kbase + i) * 128 + c]);
}

// ---------------- LDS-staged multi-split: partition edges into dst-range buckets ---------
// packed edge record: (src << 11) | (dst & 2047)   [src < 2^17, bucket-local dst 11 bits]
#define PNBK 64
#define PCAP 128
#define PEPB 2048
__global__ __launch_bounds__(256)
void k_part(const int* __restrict__ src, const int* __restrict__ dst,
            int* __restrict__ bcur, uint* __restrict__ ebuf, int E) {
  __shared__ uint stage[PNBK][PCAP];
  __shared__ int lcnt[PNBK];
  int tid = threadIdx.x;
  if (tid < PNBK) lcnt[tid] = 0;
  __syncthreads();
  int e0 = blockIdx.x * PEPB;
  for (int r = 0; r < PEPB / 256; ++r) {
    int e = e0 + r * 256 + tid;
    if (e < E) {
      int d = dst[e], s = src[e];
      int b = d >> 11;
      uint pk = ((uint)s << 11) | (uint)(d & 2047);
      int pos = atomicAdd(&lcnt[b], 1);
      if (pos < PCAP) {
        stage[b][pos] = pk;
      } else {  // overflow fallback (correct for any data)
        int p = atomicAdd(&bcur[b], 1);
        ebuf[p] = pk;
      }
    }
    if (r == 3 || r == PEPB / 256 - 1) {
      __syncthreads();
      if (tid < PNBK) {
        int c = lcnt[tid];
        if (c > PCAP) c = PCAP;
        if (c > 0) {
          int base = atomicAdd(&bcur[tid], c);
          for (int i = 0; i < c; ++i) ebuf[base + i] = stage[tid][i];
          lcnt[tid] = 0;
        }
      }
      __syncthreads();
    }
  }
}

// ---------------- per-bucket LDS counting sort (packed ebuf) ----------------
__global__ __launch_bounds__(1024)
void k_sort(const uint* __restrict__ ebuf, const int* __restrict__ bcur,
            int* __restrict__ rowbeg, int* __restrict__ rowend,
            int* __restrict__ csr, int N) {
  __shared__ int lcnt[2048];
  __shared__ int loff[2048];
  __shared__ int wsum[16];
  const int b = blockIdx.x;
  const int tid = threadIdx.x;
  const int lane = tid & 63, w = tid >> 6;
  const int base_e = b * ECAP;
  const int node0 = b << 11;
  const int ecnt = bcur[b] - base_e;

  lcnt[tid] = 0; lcnt[tid + 1024] = 0;
  __syncthreads();
  for (int i = tid; i < ecnt; i += 1024) {
    int dloc = (int)(ebuf[base_e + i] & 2047u);
    atomicAdd(&lcnt[dloc], 1);
  }
  __syncthreads();
  int v0 = lcnt[2 * tid], v1 = lcnt[2 * tid + 1];
  int s = v0 + v1;
  for (int off = 1; off < 64; off <<= 1) {
    int t = __shfl_up(s, off);
    if (lane >= off) s += t;
  }
  if (lane == 63) wsum[w] = s;
  __syncthreads();
  if (w == 0 && lane < 16) {
    int x = wsum[lane];
    int sx = x;
    for (int off = 1; off < 16; off <<= 1) {
      int t = __shfl_up(sx, off);
      if (lane >= off) sx += t;
    }
    wsum[lane] = sx - x;
  }
  __syncthreads();
  int excl = wsum[w] + (s - v0 - v1);
  loff[2 * tid] = excl;
  loff[2 * tid + 1] = excl + v0;
  __syncthreads();
  for (int i = tid; i < 2048; i += 1024) {
    int g = node0 + i;
    if (g < N) {
      int rb = base_e + loff[i];
      rowbeg[g] = rb;
      rowend[g] = rb + lcnt[i];
    }
    lcnt[i] = 0;
  }
  __syncthreads();
  for (int i = tid; i < ecnt; i += 1024) {
    uint p = ebuf[base_e + i];
    int dloc = (int)(p & 2047u);
    int pos = base_e + loff[dloc] + atomicAdd(&lcnt[dloc], 1);
    csr[pos] = (int)(p >> 11);
  }
}

// ---------------- fused GIN layer: 16-row tile, 4 waves, 8 blocks/CU (R9-proven) ----------
// gather: wave w owns rows w*4..w*4+3 (full-wave 256B row loads)
// MLP:    wave w computes nt chunks {2w, 2w+1} for all 16 rows
// two LDS tiles (z in Tz, t in Tt) -> 2 barriers
__global__ __launch_bounds__(256, 8)
void k_layer(const ushort* __restrict__ H, const int* __restrict__ rowbeg,
             const int* __restrict__ rowend, const int* __restrict__ csr,
             const ushort* __restrict__ Wf1, const ushort* __restrict__ Wf2,
             const float* __restrict__ b1, const float* __restrict__ b2,
             const float* __restrict__ eps, int layer,
             ushort* __restrict__ Hout, const int* __restrict__ batch,
             float* __restrict__ pool, int col_off, int M) {
  __shared__ uint Tz[1024];   // 16 rows x 64 uints (bf16x2), XOR-swizzled
  __shared__ uint Tt[1024];
  const int tid = threadIdx.x;
  const int w = tid >> 6, lane = tid & 63;
  const int m0 = blockIdx.x * 16;
  const float e = 1.0f + eps[layer];
  const uint* h32 = (const uint*)H;

  // ---- phase A: gather z rows (4 per wave) ----
  for (int r = 0; r < 4; ++r) {
    const int row = w * 4 + r;
    const int n = m0 + row;
    if (n < M) {
      uint u = h32[(size_t)n * 64 + lane];
      float a0 = bfu_lo(u) * e, a1 = bfu_hi(u) * e;
      int s0 = rowbeg[n], s1 = rowend[n];
      for (int base = s0; base < s1; base += 64) {
        int cnt = s1 - base;
        if (cnt > 64) cnt = 64;
        int idx = (lane < cnt) ? csr[base + lane] : 0;
        int j = 0;
        for (; j + 4 <= cnt; j += 4) {
          int i0 = __shfl(idx, j), i1 = __shfl(idx, j + 1);
          int i2 = __shfl(idx, j + 2), i3 = __shfl(idx, j + 3);
          uint u0 = h32[(size_t)i0 * 64 + lane];
          uint u1 = h32[(size_t)i1 * 64 + lane];
          uint u2 = h32[(size_t)i2 * 64 + lane];
          uint u3 = h32[(size_t)i3 * 64 + lane];
          a0 += bfu_lo(u0); a1 += bfu_hi(u0);
          a0 += bfu_lo(u1); a1 += bfu_hi(u1);
          a0 += bfu_lo(u2); a1 += bfu_hi(u2);
          a0 += bfu_lo(u3); a1 += bfu_hi(u3);
        }
        for (; j < cnt; ++j) {
          int si = __shfl(idx, j);
          uint uu = h32[(size_t)si * 64 + lane];
          a0 += bfu_lo(uu); a1 += bfu_hi(uu);
        }
      }
      Tz[row * 64 + (lane ^ ((row & 7) << 2))] = (uint)f2bf(a0) | ((uint)f2bf(a1) << 16);
    }
  }
  __syncthreads();

  // ---- phase B: GEMM1 (read Tz) -> relu -> Tt ----
  const int row16 = lane & 15, hi = lane >> 4;
  const int c2 = w << 1;
  const s16x8* wf1 = (const s16x8*)Wf1;
  f32x4 acc0 = (f32x4){0.f, 0.f, 0.f, 0.f};
  f32x4 acc1 = (f32x4){0.f, 0.f, 0.f, 0.f};
#pragma unroll
  for (int ks = 0; ks < 4; ++ks) {
    const s16x8 af = *(const s16x8*)(Tz + row16 * 64 + ((ks * 16 + hi * 4) ^ ((row16 & 7) << 2)));
    acc0 = __builtin_amdgcn_mfma_f32_16x16x32_bf16(af, wf1[((c2 + 0) * 4 + ks) * 64 + lane], acc0, 0, 0, 0);
    acc1 = __builtin_amdgcn_mfma_f32_16x16x32_bf16(af, wf1[((c2 + 1) * 4 + ks) * 64 + lane], acc1, 0, 0, 0);
  }
  {
    ushort* Tb = (ushort*)Tt;
    const float bb0 = b1[(c2 + 0) * 16 + row16];
    const float bb1 = b1[(c2 + 1) * 16 + row16];
#pragma unroll
    for (int i = 0; i < 4; ++i) {
      const int rr = hi * 4 + i;
      Tb[(rr * 128 + (c2 + 0) * 16 + row16) ^ ((rr & 7) << 3)] = f2bf(fmaxf(acc0[i] + bb0, 0.f));
      Tb[(rr * 128 + (c2 + 1) * 16 + row16) ^ ((rr & 7) << 3)] = f2bf(fmaxf(acc1[i] + bb1, 0.f));
    }
  }
  __syncthreads();

  // ---- phase C: GEMM2 (read Tt) + write + pool ----
  const s16x8* wf2 = (const s16x8*)Wf2;
  f32x4 ac0 = (f32x4){0.f, 0.f, 0.f, 0.f};
  f32x4 ac1 = (f32x4){0.f, 0.f, 0.f, 0.f};
#pragma unroll
  for (int ks = 0; ks < 4; ++ks) {
    const s16x8 af = *(const s16x8*)(Tt + row16 * 64 + ((ks * 16 + hi * 4) ^ ((row16 & 7) << 2)));
    ac0 = __builtin_amdgcn_mfma_f32_16x16x32_bf16(af, wf2[((c2 + 0) * 4 + ks) * 64 + lane], ac0, 0, 0, 0);
    ac1 = __builtin_amdgcn_mfma_f32_16x16x32_bf16(af, wf2[((c2 + 1) * 4 + ks) * 64 + lane], ac1, 0, 0, 0);
  }
  {
    const int r0 = m0 + hi * 4;
    const int col0 = (c2 + 0) * 16 + row16, col1 = (c2 + 1) * 16 + row16;
    const float bb0 = b2[col0], bb1 = b2[col1];
    const bool full = (m0 + 15 < M);
    const int gf = batch[m0 < M ? m0 : (M - 1)];
    const int gl = batch[(m0 + 15) < M ? (m0 + 15) : (M - 1)];
    if (full && gf == gl) {
      float vs0 = 0.f, vs1 = 0.f;
#pragma unroll
      for (int i = 0; i < 4; ++i) {
        float v0 = ac0[i] + bb0, v1 = ac1[i] + bb1;
        Hout[(size_t)(r0 + i) * 128 + col0] = f2bf(v0);
        Hout[(size_t)(r0 + i) * 128 + col1] = f2bf(v1);
        vs0 += v0; vs1 += v1;
      }
      vs0 += __shfl_xor(vs0, 16); vs0 += __shfl_xor(vs0, 32);
      vs1 += __shfl_xor(vs1, 16); vs1 += __shfl_xor(vs1, 32);
      if (lane < 16) {
        atomicAdd(&pool[(size_t)gf * 384 + col_off + (c2 + 0) * 16 + lane], vs0);
        atomicAdd(&pool[(size_t)gf * 384 + col_off + (c2 + 1) * 16 + lane], vs1);
      }
    } else {
#pragma unroll
      for (int i = 0; i < 4; ++i) {
        const int rr = r0 + i;
        if (rr < M) {
          float v0 = ac0[i] + bb0, v1 = ac1[i] + bb1;
          Hout[(size_t)rr * 128 + col0] = f2bf(v0);
          Hout[(size_t)rr * 128 + col1] = f2bf(v1);
          int g = batch[rr];
          atomicAdd(&pool[(size_t)g * 384 + col_off + col0], v0);
          atomicAdd(&pool[(size_t)g * 384 + col_off + col1], v1);
        }
      }
    }
  }
}

// ---------------- fused pre-MLP: h = relu(relu(x@Wp1+bp1)@Wp2+bp2), x f32 ----------------
__global__ __launch_bounds__(256, 4)
void k_mlp2(const float* __restrict__ X, const ushort* __restrict__ Wf1,
            const ushort* __restrict__ Wf2, const float* __restrict__ b1,
            const float* __restrict__ b2, ushort* __restrict__ Hout, int M) {
  __shared__ uint lt[4][1024];
  const int lane = threadIdx.x & 63;
  const int wid = threadIdx.x >> 6;
  uint* T = lt[wid];
  const int m0 = blockIdx.x * 64 + wid * 16;
  if (m0 >= M) return;
  const int row = lane & 15, hi = lane >> 4;

  f32x4 acc[8];
#pragma unroll
  for (int nt = 0; nt < 8; ++nt) acc[nt] = (f32x4){0.f, 0.f, 0.f, 0.f};
  {
    const float* xrow = X + (size_t)(m0 + row) * 128;
    const s16x8* wf = (const s16x8*)Wf1;
#pragma unroll
    for (int ks = 0; ks < 4; ++ks) {
      float4 xa = *(const float4*)&xrow[ks * 32 + hi * 8];
      float4 xb = *(const float4*)&xrow[ks * 32 + hi * 8 + 4];
      s16x8 af;
      af[0] = (short)f2bf(xa.x); af[1] = (short)f2bf(xa.y);
      af[2] = (short)f2bf(xa.z); af[3] = (short)f2bf(xa.w);
      af[4] = (short)f2bf(xb.x); af[5] = (short)f2bf(xb.y);
      af[6] = (short)f2bf(xb.z); af[7] = (short)f2bf(xb.w);
#pragma unroll
      for (int nt = 0; nt < 8; ++nt)
        acc[nt] = __builtin_amdgcn_mfma_f32_16x16x32_bf16(af, wf[(nt * 4 + ks) * 64 + lane], acc[nt], 0, 0, 0);
    }
  }
  {
    ushort* Tb = (ushort*)T;
    const int r0l = hi * 4;
#pragma unroll
    for (int nt = 0; nt < 8; ++nt) {
      float bb = b1[nt * 16 + row];
      const int col = nt * 16 + row;
#pragma unroll
      for (int i = 0; i < 4; ++i) {
        int lr = r0l + i;
        float v = fmaxf(acc[nt][i] + bb, 0.f);
        Tb[(lr * 128 + col) ^ ((lr & 7) << 3)] = f2bf(v);
      }
    }
  }
#pragma unroll
  for (int nt = 0; nt < 8; ++nt) acc[nt] = (f32x4){0.f, 0.f, 0.f, 0.f};
  {
#pragma unroll
    for (int ks = 0; ks < 4; ++ks) {
      int ub = row * 64 + ((ks * 16 + hi * 4) ^ ((row & 7) << 2));
      s16x8 af = *(const s16x8*)(T + ub);
#pragma unroll
      for (int nt = 0; nt < 8; ++nt)
        acc[nt] = __builtin_amdgcn_mfma_f32_16x16x32_bf16(af, ((const s16x8*)Wf2)[(nt * 4 + ks) * 64 + lane], acc[nt], 0, 0, 0);
    }
  }
  {
    const int r0 = m0 + hi * 4;
#pragma unroll
    for (int nt = 0; nt < 8; ++nt) {
      const int col = nt * 16 + row;
      float bb = b2[col];
#pragma unroll
      for (int i = 0; i < 4; ++i) {
        float v = fmaxf(acc[nt][i] + bb, 0.f);
        Hout[(size_t)(r0 + i) * 128 + col] = f2bf(v);
      }
    }
  }
}

extern "C" void kernel_launch(void* const* d_in, const int* in_sizes, int n_in,
                              void* d_out, int out_size, void* d_ws, size_t ws_size,
                              hipStream_t stream) {
  const float* x    = (const float*)d_in[0];
  const int*   ei   = (const int*)d_in[1];
  const int*   batch= (const int*)d_in[2];
  const float* Wp1  = (const float*)d_in[3];
  const float* bp1  = (const float*)d_in[4];
  const float* Wp2  = (const float*)d_in[5];
  const float* bp2  = (const float*)d_in[6];
  const float* W1s  = (const float*)d_in[7];
  const float* b1s  = (const float*)d_in[8];
  const float* W2s  = (const float*)d_in[9];
  const float* b2s  = (const float*)d_in[10];
  const float* eps  = (const float*)d_in[11];

  const int N = in_sizes[0] / 128;
  const int E = in_sizes[1] / 2;
  float* out = (float*)d_out;
  const int nbk = (N + 2047) >> 11;

  char* ws = (char*)d_ws;
  size_t off = 0;
  auto alloc = [&](size_t bytes) -> void* {
    void* p = ws + off;
    off += (bytes + 255) & ~(size_t)255;
    return p;
  };
  ushort* bufA  = (ushort*)alloc((size_t)N * 128 * 2);
  ushort* bufB  = (ushort*)alloc((size_t)N * 128 * 2);
  ushort* Wf    = (ushort*)alloc((size_t)8 * 16384 * 2);
  int* rowbeg   = (int*)alloc((size_t)N * 4);
  int* rowend   = (int*)alloc((size_t)N * 4);
  int* csr      = (int*)alloc((size_t)nbk * ECAP * 4);
  uint* ebuf    = (uint*)alloc((size_t)nbk * ECAP * 4);
  int* bcur     = (int*)alloc((size_t)(nbk + 1) * 4);
  (void)ws_size; (void)n_in;

  k_prepw<<<64, 256, 0, stream>>>(Wp1, Wp2, W1s, W2s, Wf, bcur, nbk, out, out_size);
  k_part<<<(E + PEPB - 1) / PEPB, 256, 0, stream>>>(ei, ei + E, bcur, ebuf, E);
  k_sort<<<nbk, 1024, 0, stream>>>(ebuf, bcur, rowbeg, rowend, csr, N);

  const int ngrid = (N + 63) / 64;
  k_mlp2<<<ngrid, 256, 0, stream>>>(x, Wf + 0 * 16384, Wf + 1 * 16384, bp1, bp2, bufA, N);

  const int lgrid = (N + 15) / 16;
  ushort* hin = bufA;
  ushort* hout = bufB;
  for (int L = 0; L < 3; ++L) {
    k_layer<<<lgrid, 256, 0, stream>>>(hin, rowbeg, rowend, csr,
                                       Wf + (2 + L) * 16384, Wf + (5 + L) * 16384,
                                       b1s + (size_t)L * 128, b2s + (size_t)L * 128,
                                       eps, L, hout, batch, out, L * 128, N);
    ushort* tmp = hin; hin = hout; hout = tmp;
  }
}

// Round 13
// 338.254 us; speedup vs baseline: 4.0152x; 1.0388x over previous
//
#include <hip/hip_runtime.h>

typedef float f32x4 __attribute__((ext_vector_type(4)));
typedef short s16x8 __attribute__((ext_vector_type(8)));

#define ECAP 36864   // padded per-bucket edge capacity (mean 32768, +22 sigma)

__device__ __forceinline__ ushort f2bf(float f) {
  uint u = __builtin_bit_cast(uint, f);
  u += 0x7fffu + ((u >> 16) & 1u);
  return (ushort)(u >> 16);
}
__device__ __forceinline__ float bfu_lo(uint u) { return __builtin_bit_cast(float, u << 16); }
__device__ __forceinline__ float bfu_hi(uint u) { return __builtin_bit_cast(float, u & 0xffff0000u); }

// f32 -> e4m3-style byte (RNE; values < 2^-7 flush to 0; our decoder is the exact inverse
// for all encodable magnitudes, em=0 treated as zero-ish)
__device__ __forceinline__ uint enc8(float f) {
  uint u = __builtin_bit_cast(uint, f);
  uint s = (u >> 24) & 0x80u;
  uint a = u & 0x7fffffffu;
  uint r = a + 0x7ffffu + ((a >> 20) & 1u);
  int em = (int)(r >> 20) - 960;          // 960 = 120<<3
  em = em < 0 ? 0 : (em > 126 ? 126 : em);
  return s | (uint)em;
}
// decode 2 packed fp8 (lo byte = even col, hi byte = odd col) -> 2 f32
// em==0 decodes to +/-2^-7 (negligible bias; see analysis)
__device__ __forceinline__ void dec8(uint u, float& f0, float& f1) {
  uint v = u | (u << 8);
  uint p = (((v & 0x007f007fu) << 4) + 0x3C003C00u) | ((v & 0x00800080u) << 8);
  f0 = __builtin_bit_cast(float, p << 16);
  f1 = __builtin_bit_cast(float, p & 0xffff0000u);
}

// ---------------- reformat 8 weight matrices into MFMA B-fragment order ----------------
// also initializes bcur and zeroes the pool output
__global__ void k_prepw(const float* __restrict__ Wp1, const float* __restrict__ Wp2,
                        const float* __restrict__ W1s, const float* __restrict__ W2s,
                        ushort* __restrict__ Wf, int* __restrict__ bcur, int nbk,
                        float* __restrict__ out, int out_size) {
  int t = blockIdx.x * blockDim.x + threadIdx.x;
  if (t <= nbk) bcur[t] = t * ECAP;
  for (int i = t; i < out_size; i += 16384) out[i] = 0.f;
  if (t >= 8 * 2048) return;
  int m = t >> 11;
  int r = t & 2047;
  int lane = r & 63;
  int ksnt = r >> 6;
  int ks = ksnt & 3;
  int nt = ksnt >> 2;
  const float* src = (m == 0) ? Wp1 : (m == 1) ? Wp2
                     : (m < 5) ? (W1s + (size_t)(m - 2) * 16384)
                               : (W2s + (size_t)(m - 5) * 16384);
  ushort* dst = Wf + (size_t)m * 16384 + (size_t)r * 8;
  int c = nt * 16 + (lane & 15);
  int kbase = ks * 32 + (lane >> 4) * 8;
  for (int i = 0; i < 8; ++i) dst[i] = f2bf(src[(size_t)(kbase + i) * 128 + c]);
}

// ---------------- LDS-staged multi-split (packed records) ----------------
#define PNBK 64
#define PCAP 128
#define PEPB 2048
__global__ __launch_bounds__(256)
void k_part(const int* __restrict__ src, const int* __restrict__ dst,
            int* __restrict__ bcur, uint* __restrict__ ebuf, int E) {
  __shared__ uint stage[PNBK][PCAP];
  __shared__ int lcnt[PNBK];
  int tid = threadIdx.x;
  if (tid < PNBK) lcnt[tid] = 0;
  __syncthreads();
  int e0 = blockIdx.x * PEPB;
  for (int r = 0; r < PEPB / 256; ++r) {
    int e = e0 + r * 256 + tid;
    if (e < E) {
      int d = dst[e], s = src[e];
      int b = d >> 11;
      uint pk = ((uint)s << 11) | (uint)(d & 2047);
      int pos = atomicAdd(&lcnt[b], 1);
      if (pos < PCAP) {
        stage[b][pos] = pk;
      } else {
        int p = atomicAdd(&bcur[b], 1);
        ebuf[p] = pk;
      }
    }
    if (r == 3 || r == PEPB / 256 - 1) {
      __syncthreads();
      if (tid < PNBK) {
        int c = lcnt[tid];
        if (c > PCAP) c = PCAP;
        if (c > 0) {
          int base = atomicAdd(&bcur[tid], c);
          for (int i = 0; i < c; ++i) ebuf[base + i] = stage[tid][i];
          lcnt[tid] = 0;
        }
      }
      __syncthreads();
    }
  }
}

// ---------------- per-bucket LDS counting sort (packed ebuf) ----------------
__global__ __launch_bounds__(1024)
void k_sort(const uint* __restrict__ ebuf, const int* __restrict__ bcur,
            int* __restrict__ rowbeg, int* __restrict__ rowend,
            int* __restrict__ csr, int N) {
  __shared__ int lcnt[2048];
  __shared__ int loff[2048];
  __shared__ int wsum[16];
  const int b = blockIdx.x;
  const int tid = threadIdx.x;
  const int lane = tid & 63, w = tid >> 6;
  const int base_e = b * ECAP;
  const int node0 = b << 11;
  const int ecnt = bcur[b] - base_e;

  lcnt[tid] = 0; lcnt[tid + 1024] = 0;
  __syncthreads();
  for (int i = tid; i < ecnt; i += 1024) {
    int dloc = (int)(ebuf[base_e + i] & 2047u);
    atomicAdd(&lcnt[dloc], 1);
  }
  __syncthreads();
  int v0 = lcnt[2 * tid], v1 = lcnt[2 * tid + 1];
  int s = v0 + v1;
  for (int off = 1; off < 64; off <<= 1) {
    int t = __shfl_up(s, off);
    if (lane >= off) s += t;
  }
  if (lane == 63) wsum[w] = s;
  __syncthreads();
  if (w == 0 && lane < 16) {
    int x = wsum[lane];
    int sx = x;
    for (int off = 1; off < 16; off <<= 1) {
      int t = __shfl_up(sx, off);
      if (lane >= off) sx += t;
    }
    wsum[lane] = sx - x;
  }
  __syncthreads();
  int excl = wsum[w] + (s - v0 - v1);
  loff[2 * tid] = excl;
  loff[2 * tid + 1] = excl + v0;
  __syncthreads();
  for (int i = tid; i < 2048; i += 1024) {
    int g = node0 + i;
    if (g < N) {
      int rb = base_e + loff[i];
      rowbeg[g] = rb;
      rowend[g] = rb + lcnt[i];
    }
    lcnt[i] = 0;
  }
  __syncthreads();
  for (int i = tid; i < ecnt; i += 1024) {
    uint p = ebuf[base_e + i];
    int dloc = (int)(p & 2047u);
    int pos = base_e + loff[dloc] + atomicAdd(&lcnt[dloc], 1);
    csr[pos] = (int)(p >> 11);
  }
}

// ---------------- fused GIN layer: fp8 neighbor gather, bf16 self/MLP ----------------
__global__ __launch_bounds__(256, 8)
void k_layer(const ushort* __restrict__ H, const unsigned char* __restrict__ H8,
             const int* __restrict__ rowbeg, const int* __restrict__ rowend,
             const int* __restrict__ csr,
             const ushort* __restrict__ Wf1, const ushort* __restrict__ Wf2,
             const float* __restrict__ b1, const float* __restrict__ b2,
             const float* __restrict__ eps, int layer,
             ushort* __restrict__ Hout, unsigned char* __restrict__ H8out,
             const int* __restrict__ batch, float* __restrict__ pool,
             int col_off, int M, int write_next) {
  __shared__ uint Tz[1024];
  __shared__ uint Tt[1024];
  const int tid = threadIdx.x;
  const int w = tid >> 6, lane = tid & 63;
  const int m0 = blockIdx.x * 16;
  const float e = 1.0f + eps[layer];
  const uint* h32 = (const uint*)H;
  const ushort* h8 = (const ushort*)H8;   // 2 fp8 per ushort, 64 per row

  // ---- phase A: gather z rows (4 per wave), neighbors from fp8 table ----
  for (int r = 0; r < 4; ++r) {
    const int row = w * 4 + r;
    const int n = m0 + row;
    if (n < M) {
      uint u = h32[(size_t)n * 64 + lane];
      float a0 = bfu_lo(u) * e, a1 = bfu_hi(u) * e;   // self term, bf16
      int s0 = rowbeg[n], s1 = rowend[n];
      for (int base = s0; base < s1; base += 64) {
        int cnt = s1 - base;
        if (cnt > 64) cnt = 64;
        int idx = (lane < cnt) ? csr[base + lane] : 0;
        int j = 0;
        for (; j + 4 <= cnt; j += 4) {
          int i0 = __shfl(idx, j), i1 = __shfl(idx, j + 1);
          int i2 = __shfl(idx, j + 2), i3 = __shfl(idx, j + 3);
          uint u0 = h8[(size_t)i0 * 64 + lane];
          uint u1 = h8[(size_t)i1 * 64 + lane];
          uint u2 = h8[(size_t)i2 * 64 + lane];
          uint u3 = h8[(size_t)i3 * 64 + lane];
          float f0, f1;
          dec8(u0, f0, f1); a0 += f0; a1 += f1;
          dec8(u1, f0, f1); a0 += f0; a1 += f1;
          dec8(u2, f0, f1); a0 += f0; a1 += f1;
          dec8(u3, f0, f1); a0 += f0; a1 += f1;
        }
        for (; j < cnt; ++j) {
          int si = __shfl(idx, j);
          uint uu = h8[(size_t)si * 64 + lane];
          float f0, f1;
          dec8(uu, f0, f1); a0 += f0; a1 += f1;
        }
      }
      Tz[row * 64 + (lane ^ ((row & 7) << 2))] = (uint)f2bf(a0) | ((uint)f2bf(a1) << 16);
    }
  }
  __syncthreads();

  // ---- phase B: GEMM1 (read Tz) -> relu -> Tt ----
  const int row16 = lane & 15, hi = lane >> 4;
  const int c2 = w << 1;
  const s16x8* wf1 = (const s16x8*)Wf1;
  f32x4 acc0 = (f32x4){0.f, 0.f, 0.f, 0.f};
  f32x4 acc1 = (f32x4){0.f, 0.f, 0.f, 0.f};
#pragma unroll
  for (int ks = 0; ks < 4; ++ks) {
    const s16x8 af = *(const s16x8*)(Tz + row16 * 64 + ((ks * 16 + hi * 4) ^ ((row16 & 7) << 2)));
    acc0 = __builtin_amdgcn_mfma_f32_16x16x32_bf16(af, wf1[((c2 + 0) * 4 + ks) * 64 + lane], acc0, 0, 0, 0);
    acc1 = __builtin_amdgcn_mfma_f32_16x16x32_bf16(af, wf1[((c2 + 1) * 4 + ks) * 64 + lane], acc1, 0, 0, 0);
  }
  {
    ushort* Tb = (ushort*)Tt;
    const float bb0 = b1[(c2 + 0) * 16 + row16];
    const float bb1 = b1[(c2 + 1) * 16 + row16];
#pragma unroll
    for (int i = 0; i < 4; ++i) {
      const int rr = hi * 4 + i;
      Tb[(rr * 128 + (c2 + 0) * 16 + row16) ^ ((rr & 7) << 3)] = f2bf(fmaxf(acc0[i] + bb0, 0.f));
      Tb[(rr * 128 + (c2 + 1) * 16 + row16) ^ ((rr & 7) << 3)] = f2bf(fmaxf(acc1[i] + bb1, 0.f));
    }
  }
  __syncthreads();

  // ---- phase C: GEMM2 (read Tt) + write bf16 + fp8 + pool ----
  const s16x8* wf2 = (const s16x8*)Wf2;
  f32x4 ac0 = (f32x4){0.f, 0.f, 0.f, 0.f};
  f32x4 ac1 = (f32x4){0.f, 0.f, 0.f, 0.f};
#pragma unroll
  for (int ks = 0; ks < 4; ++ks) {
    const s16x8 af = *(const s16x8*)(Tt + row16 * 64 + ((ks * 16 + hi * 4) ^ ((row16 & 7) << 2)));
    ac0 = __builtin_amdgcn_mfma_f32_16x16x32_bf16(af, wf2[((c2 + 0) * 4 + ks) * 64 + lane], ac0, 0, 0, 0);
    ac1 = __builtin_amdgcn_mfma_f32_16x16x32_bf16(af, wf2[((c2 + 1) * 4 + ks) * 64 + lane], ac1, 0, 0, 0);
  }
  {
    const int r0 = m0 + hi * 4;
    const int col0 = (c2 + 0) * 16 + row16, col1 = (c2 + 1) * 16 + row16;
    const float bb0 = b2[col0], bb1 = b2[col1];
    const bool full = (m0 + 15 < M);
    const int gf = batch[m0 < M ? m0 : (M - 1)];
    const int gl = batch[(m0 + 15) < M ? (m0 + 15) : (M - 1)];
    if (full && gf == gl) {
      float vs0 = 0.f, vs1 = 0.f;
#pragma unroll
      for (int i = 0; i < 4; ++i) {
        float v0 = ac0[i] + bb0, v1 = ac1[i] + bb1;
        if (write_next) {
          Hout[(size_t)(r0 + i) * 128 + col0] = f2bf(v0);
          Hout[(size_t)(r0 + i) * 128 + col1] = f2bf(v1);
          H8out[(size_t)(r0 + i) * 128 + col0] = (unsigned char)enc8(v0);
          H8out[(size_t)(r0 + i) * 128 + col1] = (unsigned char)enc8(v1);
        }
        vs0 += v0; vs1 += v1;
      }
      vs0 += __shfl_xor(vs0, 16); vs0 += __shfl_xor(vs0, 32);
      vs1 += __shfl_xor(vs1, 16); vs1 += __shfl_xor(vs1, 32);
      if (lane < 16) {
        atomicAdd(&pool[(size_t)gf * 384 + col_off + (c2 + 0) * 16 + lane], vs0);
        atomicAdd(&pool[(size_t)gf * 384 + col_off + (c2 + 1) * 16 + lane], vs1);
      }
    } else {
#pragma unroll
      for (int i = 0; i < 4; ++i) {
        const int rr = r0 + i;
        if (rr < M) {
          float v0 = ac0[i] + bb0, v1 = ac1[i] + bb1;
          if (write_next) {
            Hout[(size_t)rr * 128 + col0] = f2bf(v0);
            Hout[(size_t)rr * 128 + col1] = f2bf(v1);
            H8out[(size_t)rr * 128 + col0] = (unsigned char)enc8(v0);
            H8out[(size_t)rr * 128 + col1] = (unsigned char)enc8(v1);
          }
          int g = batch[rr];
          atomicAdd(&pool[(size_t)g * 384 + col_off + col0], v0);
          atomicAdd(&pool[(size_t)g * 384 + col_off + col1], v1);
        }
      }
    }
  }
}

// ---------------- fused pre-MLP: writes bf16 h0 and fp8 h0 ----------------
__global__ __launch_bounds__(256, 4)
void k_mlp2(const float* __restrict__ X, const ushort* __restrict__ Wf1,
            const ushort* __restrict__ Wf2, const float* __restrict__ b1,
            const float* __restrict__ b2, ushort* __restrict__ Hout,
            unsigned char* __restrict__ H8out, int M) {
  __shared__ uint lt[4][1024];
  const int lane = threadIdx.x & 63;
  const int wid = threadIdx.x >> 6;
  uint* T = lt[wid];
  const int m0 = blockIdx.x * 64 + wid * 16;
  if (m0 >= M) return;
  const int row = lane & 15, hi = lane >> 4;

  f32x4 acc[8];
#pragma unroll
  for (int nt = 0; nt < 8; ++nt) acc[nt] = (f32x4){0.f, 0.f, 0.f, 0.f};
  {
    const float* xrow = X + (size_t)(m0 + row) * 128;
    const s16x8* wf = (const s16x8*)Wf1;
#pragma unroll
    for (int ks = 0; ks < 4; ++ks) {
      float4 xa = *(const float4*)&xrow[ks * 32 + hi * 8];
      float4 xb = *(const float4*)&xrow[ks * 32 + hi * 8 + 4];
      s16x8 af;
      af[0] = (short)f2bf(xa.x); af[1] = (short)f2bf(xa.y);
      af[2] = (short)f2bf(xa.z); af[3] = (short)f2bf(xa.w);
      af[4] = (short)f2bf(xb.x); af[5] = (short)f2bf(xb.y);
      af[6] = (short)f2bf(xb.z); af[7] = (short)f2bf(xb.w);
#pragma unroll
      for (int nt = 0; nt < 8; ++nt)
        acc[nt] = __builtin_amdgcn_mfma_f32_16x16x32_bf16(af, wf[(nt * 4 + ks) * 64 + lane], acc[nt], 0, 0, 0);
    }
  }
  {
    ushort* Tb = (ushort*)T;
    const int r0l = hi * 4;
#pragma unroll
    for (int nt = 0; nt < 8; ++nt) {
      float bb = b1[nt * 16 + row];
      const int col = nt * 16 + row;
#pragma unroll
      for (int i = 0; i < 4; ++i) {
        int lr = r0l + i;
        float v = fmaxf(acc[nt][i] + bb, 0.f);
        Tb[(lr * 128 + col) ^ ((lr & 7) << 3)] = f2bf(v);
      }
    }
  }
#pragma unroll
  for (int nt = 0; nt < 8; ++nt) acc[nt] = (f32x4){0.f, 0.f, 0.f, 0.f};
  {
#pragma unroll
    for (int ks = 0; ks < 4; ++ks) {
      int ub = row * 64 + ((ks * 16 + hi * 4) ^ ((row & 7) << 2));
      s16x8 af = *(const s16x8*)(T + ub);
#pragma unroll
      for (int nt = 0; nt < 8; ++nt)
        acc[nt] = __builtin_amdgcn_mfma_f32_16x16x32_bf16(af, ((const s16x8*)Wf2)[(nt * 4 + ks) * 64 + lane], acc[nt], 0, 0, 0);
    }
  }
  {
    const int r0 = m0 + hi * 4;
#pragma unroll
    for (int nt = 0; nt < 8; ++nt) {
      const int col = nt * 16 + row;
      float bb = b2[col];
#pragma unroll
      for (int i = 0; i < 4; ++i) {
        float v = fmaxf(acc[nt][i] + bb, 0.f);
        Hout[(size_t)(r0 + i) * 128 + col] = f2bf(v);
        H8out[(size_t)(r0 + i) * 128 + col] = (unsigned char)enc8(v);
      }
    }
  }
}

extern "C" void kernel_launch(void* const* d_in, const int* in_sizes, int n_in,
                              void* d_out, int out_size, void* d_ws, size_t ws_size,
                              hipStream_t stream) {
  const float* x    = (const float*)d_in[0];
  const int*   ei   = (const int*)d_in[1];
  const int*   batch= (const int*)d_in[2];
  const float* Wp1  = (const float*)d_in[3];
  const float* bp1  = (const float*)d_in[4];
  const float* Wp2  = (const float*)d_in[5];
  const float* bp2  = (const float*)d_in[6];
  const float* W1s  = (const float*)d_in[7];
  const float* b1s  = (const float*)d_in[8];
  const float* W2s  = (const float*)d_in[9];
  const float* b2s  = (const float*)d_in[10];
  const float* eps  = (const float*)d_in[11];

  const int N = in_sizes[0] / 128;
  const int E = in_sizes[1] / 2;
  float* out = (float*)d_out;
  const int nbk = (N + 2047) >> 11;

  char* ws = (char*)d_ws;
  size_t off = 0;
  auto alloc = [&](size_t bytes) -> void* {
    void* p = ws + off;
    off += (bytes + 255) & ~(size_t)255;
    return p;
  };
  ushort* bufA  = (ushort*)alloc((size_t)N * 128 * 2);
  ushort* bufB  = (ushort*)alloc((size_t)N * 128 * 2);
  unsigned char* h8A = (unsigned char*)alloc((size_t)N * 128);
  unsigned char* h8B = (unsigned char*)alloc((size_t)N * 128);
  ushort* Wf    = (ushort*)alloc((size_t)8 * 16384 * 2);
  int* rowbeg   = (int*)alloc((size_t)N * 4);
  int* rowend   = (int*)alloc((size_t)N * 4);
  int* csr      = (int*)alloc((size_t)nbk * ECAP * 4);
  uint* ebuf    = (uint*)alloc((size_t)nbk * ECAP * 4);
  int* bcur     = (int*)alloc((size_t)(nbk + 1) * 4);
  (void)ws_size; (void)n_in;

  k_prepw<<<64, 256, 0, stream>>>(Wp1, Wp2, W1s, W2s, Wf, bcur, nbk, out, out_size);
  k_part<<<(E + PEPB - 1) / PEPB, 256, 0, stream>>>(ei, ei + E, bcur, ebuf, E);
  k_sort<<<nbk, 1024, 0, stream>>>(ebuf, bcur, rowbeg, rowend, csr, N);

  const int ngrid = (N + 63) / 64;
  k_mlp2<<<ngrid, 256, 0, stream>>>(x, Wf + 0 * 16384, Wf + 1 * 16384, bp1, bp2, bufA, h8A, N);

  const int lgrid = (N + 15) / 16;
  ushort* hin = bufA;
  ushort* hout = bufB;
  unsigned char* h8in = h8A;
  unsigned char* h8out = h8B;
  for (int L = 0; L < 3; ++L) {
    k_layer<<<lgrid, 256, 0, stream>>>(hin, h8in, rowbeg, rowend, csr,
                                       Wf + (2 + L) * 16384, Wf + (5 + L) * 16384,
                                       b1s + (size_t)L * 128, b2s + (size_t)L * 128,
                                       eps, L, hout, h8out, batch, out, L * 128, N,
                                       (L < 2) ? 1 : 0);
    ushort* tmp = hin; hin = hout; hout = tmp;
    unsigned char* t8 = h8in; h8in = h8out; h8out = t8;
  }
}

// Round 14
// 321.167 us; speedup vs baseline: 4.2288x; 1.0532x over previous
//
#include <hip/hip_runtime.h>

typedef float f32x2 __attribute__((ext_vector_type(2)));
typedef float f32x4 __attribute__((ext_vector_type(4)));
typedef short s16x8 __attribute__((ext_vector_type(8)));

#define ECAP 36864   // padded per-bucket edge capacity (mean 32768, +22 sigma)

#if __has_builtin(__builtin_amdgcn_cvt_pk_f32_fp8) && __has_builtin(__builtin_amdgcn_cvt_pk_fp8_f32)
#define HW_FP8 1
#else
#define HW_FP8 0
#endif

__device__ __forceinline__ ushort f2bf(float f) {
  uint u = __builtin_bit_cast(uint, f);
  u += 0x7fffu + ((u >> 16) & 1u);
  return (ushort)(u >> 16);
}
__device__ __forceinline__ float bfu_lo(uint u) { return __builtin_bit_cast(float, u << 16); }
__device__ __forceinline__ float bfu_hi(uint u) { return __builtin_bit_cast(float, u & 0xffff0000u); }

// f32 -> fp8 byte (HW OCP e4m3fn if available, else custom e4m3-style)
__device__ __forceinline__ uint enc8(float f) {
#if HW_FP8
  return (uint)(__builtin_amdgcn_cvt_pk_fp8_f32(f, f, 0, false) & 0xff);
#else
  uint u = __builtin_bit_cast(uint, f);
  uint s = (u >> 24) & 0x80u;
  uint a = u & 0x7fffffffu;
  uint r = a + 0x7ffffu + ((a >> 20) & 1u);
  int em = (int)(r >> 20) - 960;
  em = em < 0 ? 0 : (em > 126 ? 126 : em);
  return s | (uint)em;
#endif
}
// decode 2 packed fp8 (lo byte = even col, hi byte = odd col) -> 2 f32
__device__ __forceinline__ void dec8(uint u, float& f0, float& f1) {
#if HW_FP8
  f32x2 r = __builtin_amdgcn_cvt_pk_f32_fp8((int)u, false);
  f0 = r.x; f1 = r.y;
#else
  uint v = u | (u << 8);
  uint p = (((v & 0x007f007fu) << 4) + 0x3C003C00u) | ((v & 0x00800080u) << 8);
  f0 = __builtin_bit_cast(float, p << 16);
  f1 = __builtin_bit_cast(float, p & 0xffff0000u);
#endif
}

// ---------------- reformat 8 weight matrices into MFMA B-fragment order ----------------
// also initializes bcur and zeroes the pool output
__global__ void k_prepw(const float* __restrict__ Wp1, const float* __restrict__ Wp2,
                        const float* __restrict__ W1s, const float* __restrict__ W2s,
                        ushort* __restrict__ Wf, int* __restrict__ bcur, int nbk,
                        float* __restrict__ out, int out_size) {
  int t = blockIdx.x * blockDim.x + threadIdx.x;
  if (t <= nbk) bcur[t] = t * ECAP;
  for (int i = t; i < out_size; i += 16384) out[i] = 0.f;
  if (t >= 8 * 2048) return;
  int m = t >> 11;
  int r = t & 2047;
  int lane = r & 63;
  int ksnt = r >> 6;
  int ks = ksnt & 3;
  int nt = ksnt >> 2;
  const float* src = (m == 0) ? Wp1 : (m == 1) ? Wp2
                     : (m < 5) ? (W1s + (size_t)(m - 2) * 16384)
                               : (W2s + (size_t)(m - 5) * 16384);
  ushort* dst = Wf + (size_t)m * 16384 + (size_t)r * 8;
  int c = nt * 16 + (lane & 15);
  int kbase = ks * 32 + (lane >> 4) * 8;
  for (int i = 0; i < 8; ++i) dst[i] = f2bf(src[(size_t)(kbase + i) * 128 + c]);
}

// ---------------- LDS-staged multi-split (packed records) ----------------
#define PNBK 64
#define PCAP 128
#define PEPB 2048
__global__ __launch_bounds__(256)
void k_part(const int* __restrict__ src, const int* __restrict__ dst,
            int* __restrict__ bcur, uint* __restrict__ ebuf, int E) {
  __shared__ uint stage[PNBK][PCAP];
  __shared__ int lcnt[PNBK];
  int tid = threadIdx.x;
  if (tid < PNBK) lcnt[tid] = 0;
  __syncthreads();
  int e0 = blockIdx.x * PEPB;
  for (int r = 0; r < PEPB / 256; ++r) {
    int e = e0 + r * 256 + tid;
    if (e < E) {
      int d = dst[e], s = src[e];
      int b = d >> 11;
      uint pk = ((uint)s << 11) | (uint)(d & 2047);
      int pos = atomicAdd(&lcnt[b], 1);
      if (pos < PCAP) {
        stage[b][pos] = pk;
      } else {
        int p = atomicAdd(&bcur[b], 1);
        ebuf[p] = pk;
      }
    }
    if (r == 3 || r == PEPB / 256 - 1) {
      __syncthreads();
      if (tid < PNBK) {
        int c = lcnt[tid];
        if (c > PCAP) c = PCAP;
        if (c > 0) {
          int base = atomicAdd(&bcur[tid], c);
          for (int i = 0; i < c; ++i) ebuf[base + i] = stage[tid][i];
          lcnt[tid] = 0;
        }
      }
      __syncthreads();
    }
  }
}

// ---------------- per-bucket LDS counting sort (packed ebuf) ----------------
__global__ __launch_bounds__(1024)
void k_sort(const uint* __restrict__ ebuf, const int* __restrict__ bcur,
            int* __restrict__ rowbeg, int* __restrict__ rowend,
            int* __restrict__ csr, int N) {
  __shared__ int lcnt[2048];
  __shared__ int loff[2048];
  __shared__ int wsum[16];
  const int b = blockIdx.x;
  const int tid = threadIdx.x;
  const int lane = tid & 63, w = tid >> 6;
  const int base_e = b * ECAP;
  const int node0 = b << 11;
  const int ecnt = bcur[b] - base_e;

  lcnt[tid] = 0; lcnt[tid + 1024] = 0;
  __syncthreads();
  for (int i = tid; i < ecnt; i += 1024) {
    int dloc = (int)(ebuf[base_e + i] & 2047u);
    atomicAdd(&lcnt[dloc], 1);
  }
  __syncthreads();
  int v0 = lcnt[2 * tid], v1 = lcnt[2 * tid + 1];
  int s = v0 + v1;
  for (int off = 1; off < 64; off <<= 1) {
    int t = __shfl_up(s, off);
    if (lane >= off) s += t;
  }
  if (lane == 63) wsum[w] = s;
  __syncthreads();
  if (w == 0 && lane < 16) {
    int x = wsum[lane];
    int sx = x;
    for (int off = 1; off < 16; off <<= 1) {
      int t = __shfl_up(sx, off);
      if (lane >= off) sx += t;
    }
    wsum[lane] = sx - x;
  }
  __syncthreads();
  int excl = wsum[w] + (s - v0 - v1);
  loff[2 * tid] = excl;
  loff[2 * tid + 1] = excl + v0;
  __syncthreads();
  for (int i = tid; i < 2048; i += 1024) {
    int g = node0 + i;
    if (g < N) {
      int rb = base_e + loff[i];
      rowbeg[g] = rb;
      rowend[g] = rb + lcnt[i];
    }
    lcnt[i] = 0;
  }
  __syncthreads();
  for (int i = tid; i < ecnt; i += 1024) {
    uint p = ebuf[base_e + i];
    int dloc = (int)(p & 2047u);
    int pos = base_e + loff[dloc] + atomicAdd(&lcnt[dloc], 1);
    csr[pos] = (int)(p >> 11);
  }
}

// ---------------- fused GIN layer: fp8 neighbor gather (HW cvt), bf16 self/MLP ----------
__global__ __launch_bounds__(256, 8)
void k_layer(const ushort* __restrict__ H, const unsigned char* __restrict__ H8,
             const int* __restrict__ rowbeg, const int* __restrict__ rowend,
             const int* __restrict__ csr,
             const ushort* __restrict__ Wf1, const ushort* __restrict__ Wf2,
             const float* __restrict__ b1, const float* __restrict__ b2,
             const float* __restrict__ eps, int layer,
             ushort* __restrict__ Hout, unsigned char* __restrict__ H8out,
             const int* __restrict__ batch, float* __restrict__ pool,
             int col_off, int M, int write_next) {
  __shared__ uint Tz[1024];
  __shared__ uint Tt[1024];
  const int tid = threadIdx.x;
  const int w = tid >> 6, lane = tid & 63;
  const int m0 = blockIdx.x * 16;
  const float e = 1.0f + eps[layer];
  const uint* h32 = (const uint*)H;
  const ushort* h8 = (const ushort*)H8;   // 2 fp8 per ushort, 64 per row

  // ---- phase A: gather z rows (4 per wave), neighbors from fp8 table ----
  for (int r = 0; r < 4; ++r) {
    const int row = w * 4 + r;
    const int n = m0 + row;
    if (n < M) {
      uint u = h32[(size_t)n * 64 + lane];
      float a0 = bfu_lo(u) * e, a1 = bfu_hi(u) * e;   // self term, bf16
      int s0 = rowbeg[n], s1 = rowend[n];
      for (int base = s0; base < s1; base += 64) {
        int cnt = s1 - base;
        if (cnt > 64) cnt = 64;
        int idx = (lane < cnt) ? csr[base + lane] : 0;
        int j = 0;
        for (; j + 4 <= cnt; j += 4) {
          int i0 = __shfl(idx, j), i1 = __shfl(idx, j + 1);
          int i2 = __shfl(idx, j + 2), i3 = __shfl(idx, j + 3);
          uint u0 = h8[((uint)i0 << 6) | (uint)lane];
          uint u1 = h8[((uint)i1 << 6) | (uint)lane];
          uint u2 = h8[((uint)i2 << 6) | (uint)lane];
          uint u3 = h8[((uint)i3 << 6) | (uint)lane];
          float f0, f1;
          dec8(u0, f0, f1); a0 += f0; a1 += f1;
          dec8(u1, f0, f1); a0 += f0; a1 += f1;
          dec8(u2, f0, f1); a0 += f0; a1 += f1;
          dec8(u3, f0, f1); a0 += f0; a1 += f1;
        }
        for (; j < cnt; ++j) {
          int si = __shfl(idx, j);
          uint uu = h8[((uint)si << 6) | (uint)lane];
          float f0, f1;
          dec8(uu, f0, f1); a0 += f0; a1 += f1;
        }
      }
      Tz[row * 64 + (lane ^ ((row & 7) << 2))] = (uint)f2bf(a0) | ((uint)f2bf(a1) << 16);
    }
  }
  __syncthreads();

  // ---- phase B: GEMM1 (read Tz) -> relu -> Tt ----
  const int row16 = lane & 15, hi = lane >> 4;
  const int c2 = w << 1;
  const s16x8* wf1 = (const s16x8*)Wf1;
  f32x4 acc0 = (f32x4){0.f, 0.f, 0.f, 0.f};
  f32x4 acc1 = (f32x4){0.f, 0.f, 0.f, 0.f};
#pragma unroll
  for (int ks = 0; ks < 4; ++ks) {
    const s16x8 af = *(const s16x8*)(Tz + row16 * 64 + ((ks * 16 + hi * 4) ^ ((row16 & 7) << 2)));
    acc0 = __builtin_amdgcn_mfma_f32_16x16x32_bf16(af, wf1[((c2 + 0) * 4 + ks) * 64 + lane], acc0, 0, 0, 0);
    acc1 = __builtin_amdgcn_mfma_f32_16x16x32_bf16(af, wf1[((c2 + 1) * 4 + ks) * 64 + lane], acc1, 0, 0, 0);
  }
  {
    ushort* Tb = (ushort*)Tt;
    const float bb0 = b1[(c2 + 0) * 16 + row16];
    const float bb1 = b1[(c2 + 1) * 16 + row16];
#pragma unroll
    for (int i = 0; i < 4; ++i) {
      const int rr = hi * 4 + i;
      Tb[(rr * 128 + (c2 + 0) * 16 + row16) ^ ((rr & 7) << 3)] = f2bf(fmaxf(acc0[i] + bb0, 0.f));
      Tb[(rr * 128 + (c2 + 1) * 16 + row16) ^ ((rr & 7) << 3)] = f2bf(fmaxf(acc1[i] + bb1, 0.f));
    }
  }
  __syncthreads();

  // ---- phase C: GEMM2 (read Tt) + write bf16 + fp8 + pool ----
  const s16x8* wf2 = (const s16x8*)Wf2;
  f32x4 ac0 = (f32x4){0.f, 0.f, 0.f, 0.f};
  f32x4 ac1 = (f32x4){0.f, 0.f, 0.f, 0.f};
#pragma unroll
  for (int ks = 0; ks < 4; ++ks) {
    const s16x8 af = *(const s16x8*)(Tt + row16 * 64 + ((ks * 16 + hi * 4) ^ ((row16 & 7) << 2)));
    ac0 = __builtin_amdgcn_mfma_f32_16x16x32_bf16(af, wf2[((c2 + 0) * 4 + ks) * 64 + lane], ac0, 0, 0, 0);
    ac1 = __builtin_amdgcn_mfma_f32_16x16x32_bf16(af, wf2[((c2 + 1) * 4 + ks) * 64 + lane], ac1, 0, 0, 0);
  }
  {
    const int r0 = m0 + hi * 4;
    const int col0 = (c2 + 0) * 16 + row16, col1 = (c2 + 1) * 16 + row16;
    const float bb0 = b2[col0], bb1 = b2[col1];
    const bool full = (m0 + 15 < M);
    const int gf = batch[m0 < M ? m0 : (M - 1)];
    const int gl = batch[(m0 + 15) < M ? (m0 + 15) : (M - 1)];
    if (full && gf == gl) {
      float vs0 = 0.f, vs1 = 0.f;
#pragma unroll
      for (int i = 0; i < 4; ++i) {
        float v0 = ac0[i] + bb0, v1 = ac1[i] + bb1;
        if (write_next) {
          Hout[(size_t)(r0 + i) * 128 + col0] = f2bf(v0);
          Hout[(size_t)(r0 + i) * 128 + col1] = f2bf(v1);
          H8out[(size_t)(r0 + i) * 128 + col0] = (unsigned char)enc8(v0);
          H8out[(size_t)(r0 + i) * 128 + col1] = (unsigned char)enc8(v1);
        }
        vs0 += v0; vs1 += v1;
      }
      vs0 += __shfl_xor(vs0, 16); vs0 += __shfl_xor(vs0, 32);
      vs1 += __shfl_xor(vs1, 16); vs1 += __shfl_xor(vs1, 32);
      if (lane < 16) {
        atomicAdd(&pool[(size_t)gf * 384 + col_off + (c2 + 0) * 16 + lane], vs0);
        atomicAdd(&pool[(size_t)gf * 384 + col_off + (c2 + 1) * 16 + lane], vs1);
      }
    } else {
#pragma unroll
      for (int i = 0; i < 4; ++i) {
        const int rr = r0 + i;
        if (rr < M) {
          float v0 = ac0[i] + bb0, v1 = ac1[i] + bb1;
          if (write_next) {
            Hout[(size_t)rr * 128 + col0] = f2bf(v0);
            Hout[(size_t)rr * 128 + col1] = f2bf(v1);
            H8out[(size_t)rr * 128 + col0] = (unsigned char)enc8(v0);
            H8out[(size_t)rr * 128 + col1] = (unsigned char)enc8(v1);
          }
          int g = batch[rr];
          atomicAdd(&pool[(size_t)g * 384 + col_off + col0], v0);
          atomicAdd(&pool[(size_t)g * 384 + col_off + col1], v1);
        }
      }
    }
  }
}

// ---------------- fused pre-MLP: writes bf16 h0 and fp8 h0 ----------------
__global__ __launch_bounds__(256, 4)
void k_mlp2(const float* __restrict__ X, const ushort* __restrict__ Wf1,
            const ushort* __restrict__ Wf2, const float* __restrict__ b1,
            const float* __restrict__ b2, ushort* __restrict__ Hout,
            unsigned char* __restrict__ H8out, int M) {
  __shared__ uint lt[4][1024];
  const int lane = threadIdx.x & 63;
  const int wid = threadIdx.x >> 6;
  uint* T = lt[wid];
  const int m0 = blockIdx.x * 64 + wid * 16;
  if (m0 >= M) return;
  const int row = lane & 15, hi = lane >> 4;

  f32x4 acc[8];
#pragma unroll
  for (int nt = 0; nt < 8; ++nt) acc[nt] = (f32x4){0.f, 0.f, 0.f, 0.f};
  {
    const float* xrow = X + (size_t)(m0 + row) * 128;
    const s16x8* wf = (const s16x8*)Wf1;
#pragma unroll
    for (int ks = 0; ks < 4; ++ks) {
      float4 xa = *(const float4*)&xrow[ks * 32 + hi * 8];
      float4 xb = *(const float4*)&xrow[ks * 32 + hi * 8 + 4];
      s16x8 af;
      af[0] = (short)f2bf(xa.x); af[1] = (short)f2bf(xa.y);
      af[2] = (short)f2bf(xa.z); af[3] = (short)f2bf(xa.w);
      af[4] = (short)f2bf(xb.x); af[5] = (short)f2bf(xb.y);
      af[6] = (short)f2bf(xb.z); af[7] = (short)f2bf(xb.w);
#pragma unroll
      for (int nt = 0; nt < 8; ++nt)
        acc[nt] = __builtin_amdgcn_mfma_f32_16x16x32_bf16(af, wf[(nt * 4 + ks) * 64 + lane], acc[nt], 0, 0, 0);
    }
  }
  {
    ushort* Tb = (ushort*)T;
    const int r0l = hi * 4;
#pragma unroll
    for (int nt = 0; nt < 8; ++nt) {
      float bb = b1[nt * 16 + row];
      const int col = nt * 16 + row;
#pragma unroll
      for (int i = 0; i < 4; ++i) {
        int lr = r0l + i;
        float v = fmaxf(acc[nt][i] + bb, 0.f);
        Tb[(lr * 128 + col) ^ ((lr & 7) << 3)] = f2bf(v);
      }
    }
  }
#pragma unroll
  for (int nt = 0; nt < 8; ++nt) acc[nt] = (f32x4){0.f, 0.f, 0.f, 0.f};
  {
#pragma unroll
    for (int ks = 0; ks < 4; ++ks) {
      int ub = row * 64 + ((ks * 16 + hi * 4) ^ ((row & 7) << 2));
      s16x8 af = *(const s16x8*)(T + ub);
#pragma unroll
      for (int nt = 0; nt < 8; ++nt)
        acc[nt] = __builtin_amdgcn_mfma_f32_16x16x32_bf16(af, ((const s16x8*)Wf2)[(nt * 4 + ks) * 64 + lane], acc[nt], 0, 0, 0);
    }
  }
  {
    const int r0 = m0 + hi * 4;
#pragma unroll
    for (int nt = 0; nt < 8; ++nt) {
      const int col = nt * 16 + row;
      float bb = b2[col];
#pragma unroll
      for (int i = 0; i < 4; ++i) {
        float v = fmaxf(acc[nt][i] + bb, 0.f);
        Hout[(size_t)(r0 + i) * 128 + col] = f2bf(v);
        H8out[(size_t)(r0 + i) * 128 + col] = (unsigned char)enc8(v);
      }
    }
  }
}

extern "C" void kernel_launch(void* const* d_in, const int* in_sizes, int n_in,
                              void* d_out, int out_size, void* d_ws, size_t ws_size,
                              hipStream_t stream) {
  const float* x    = (const float*)d_in[0];
  const int*   ei   = (const int*)d_in[1];
  const int*   batch= (const int*)d_in[2];
  const float* Wp1  = (const float*)d_in[3];
  const float* bp1  = (const float*)d_in[4];
  const float* Wp2  = (const float*)d_in[5];
  const float* bp2  = (const float*)d_in[6];
  const float* W1s  = (const float*)d_in[7];
  const float* b1s  = (const float*)d_in[8];
  const float* W2s  = (const float*)d_in[9];
  const float* b2s  = (const float*)d_in[10];
  const float* eps  = (const float*)d_in[11];

  const int N = in_sizes[0] / 128;
  const int E = in_sizes[1] / 2;
  float* out = (float*)d_out;
  const int nbk = (N + 2047) >> 11;

  char* ws = (char*)d_ws;
  size_t off = 0;
  auto alloc = [&](size_t bytes) -> void* {
    void* p = ws + off;
    off += (bytes + 255) & ~(size_t)255;
    return p;
  };
  ushort* bufA  = (ushort*)alloc((size_t)N * 128 * 2);
  ushort* bufB  = (ushort*)alloc((size_t)N * 128 * 2);
  unsigned char* h8A = (unsigned char*)alloc((size_t)N * 128);
  unsigned char* h8B = (unsigned char*)alloc((size_t)N * 128);
  ushort* Wf    = (ushort*)alloc((size_t)8 * 16384 * 2);
  int* rowbeg   = (int*)alloc((size_t)N * 4);
  int* rowend   = (int*)alloc((size_t)N * 4);
  int* csr      = (int*)alloc((size_t)nbk * ECAP * 4);
  uint* ebuf    = (uint*)alloc((size_t)nbk * ECAP * 4);
  int* bcur     = (int*)alloc((size_t)(nbk + 1) * 4);
  (void)ws_size; (void)n_in;

  k_prepw<<<64, 256, 0, stream>>>(Wp1, Wp2, W1s, W2s, Wf, bcur, nbk, out, out_size);
  k_part<<<(E + PEPB - 1) / PEPB, 256, 0, stream>>>(ei, ei + E, bcur, ebuf, E);
  k_sort<<<nbk, 1024, 0, stream>>>(ebuf, bcur, rowbeg, rowend, csr, N);

  const int ngrid = (N + 63) / 64;
  k_mlp2<<<ngrid, 256, 0, stream>>>(x, Wf + 0 * 16384, Wf + 1 * 16384, bp1, bp2, bufA, h8A, N);

  const int lgrid = (N + 15) / 16;
  ushort* hin = bufA;
  ushort* hout = bufB;
  unsigned char* h8in = h8A;
  unsigned char* h8out = h8B;
  for (int L = 0; L < 3; ++L) {
    k_layer<<<lgrid, 256, 0, stream>>>(hin, h8in, rowbeg, rowend, csr,
                                       Wf + (2 + L) * 16384, Wf + (5 + L) * 16384,
                                       b1s + (size_t)L * 128, b2s + (size_t)L * 128,
                                       eps, L, hout, h8out, batch, out, L * 128, N,
                                       (L < 2) ? 1 : 0);
    ushort* tmp = hin; hin = hout; hout = tmp;
    unsigned char* t8 = h8in; h8in = h8out; h8out = t8;
  }
}

// Round 15
// 307.135 us; speedup vs baseline: 4.4220x; 1.0457x over previous
//
#include <hip/hip_runtime.h>

typedef float f32x2 __attribute__((ext_vector_type(2)));
typedef float f32x4 __attribute__((ext_vector_type(4)));
typedef short s16x8 __attribute__((ext_vector_type(8)));

#define ECAP 36864   // padded per-bucket edge capacity (mean 32768, +22 sigma)

#if __has_builtin(__builtin_amdgcn_cvt_pk_f32_fp8) && __has_builtin(__builtin_amdgcn_cvt_pk_fp8_f32)
#define HW_FP8 1
#else
#define HW_FP8 0
#endif

__device__ __forceinline__ ushort f2bf(float f) {
  uint u = __builtin_bit_cast(uint, f);
  u += 0x7fffu + ((u >> 16) & 1u);
  return (ushort)(u >> 16);
}
__device__ __forceinline__ float bfu_lo(uint u) { return __builtin_bit_cast(float, u << 16); }
__device__ __forceinline__ float bfu_hi(uint u) { return __builtin_bit_cast(float, u & 0xffff0000u); }

// f32 -> fp8 byte (HW OCP e4m3fn if available, else custom e4m3-style)
__device__ __forceinline__ uint enc8(float f) {
#if HW_FP8
  return (uint)(__builtin_amdgcn_cvt_pk_fp8_f32(f, f, 0, false) & 0xff);
#else
  uint u = __builtin_bit_cast(uint, f);
  uint s = (u >> 24) & 0x80u;
  uint a = u & 0x7fffffffu;
  uint r = a + 0x7ffffu + ((a >> 20) & 1u);
  int em = (int)(r >> 20) - 960;
  em = em < 0 ? 0 : (em > 126 ? 126 : em);
  return s | (uint)em;
#endif
}
// decode 2 packed fp8 (lo byte = even col, hi byte = odd col) -> 2 f32
__device__ __forceinline__ void dec8(uint u, float& f0, float& f1) {
#if HW_FP8
  f32x2 r = __builtin_amdgcn_cvt_pk_f32_fp8((int)u, false);
  f0 = r.x; f1 = r.y;
#else
  uint v = u | (u << 8);
  uint p = (((v & 0x007f007fu) << 4) + 0x3C003C00u) | ((v & 0x00800080u) << 8);
  f0 = __builtin_bit_cast(float, p << 16);
  f1 = __builtin_bit_cast(float, p & 0xffff0000u);
#endif
}

// ---------------- reformat 8 weight matrices into MFMA B-fragment order ----------------
// also initializes bcur and zeroes the pool output
__global__ void k_prepw(const float* __restrict__ Wp1, const float* __restrict__ Wp2,
                        const float* __restrict__ W1s, const float* __restrict__ W2s,
                        ushort* __restrict__ Wf, int* __restrict__ bcur, int nbk,
                        float* __restrict__ out, int out_size) {
  int t = blockIdx.x * blockDim.x + threadIdx.x;
  if (t <= nbk) bcur[t] = t * ECAP;
  for (int i = t; i < out_size; i += 16384) out[i] = 0.f;
  if (t >= 8 * 2048) return;
  int m = t >> 11;
  int r = t & 2047;
  int lane = r & 63;
  int ksnt = r >> 6;
  int ks = ksnt & 3;
  int nt = ksnt >> 2;
  const float* src = (m == 0) ? Wp1 : (m == 1) ? Wp2
                     : (m < 5) ? (W1s + (size_t)(m - 2) * 16384)
                               : (W2s + (size_t)(m - 5) * 16384);
  ushort* dst = Wf + (size_t)m * 16384 + (size_t)r * 8;
  int c = nt * 16 + (lane & 15);
  int kbase = ks * 32 + (lane >> 4) * 8;
  for (int i = 0; i < 8; ++i) dst[i] = f2bf(src[(size_t)(kbase + i) * 128 + c]);
}

// ---------------- LDS-staged multi-split (packed records) ----------------
#define PNBK 64
#define PCAP 128
#define PEPB 2048
__global__ __launch_bounds__(256)
void k_part(const int* __restrict__ src, const int* __restrict__ dst,
            int* __restrict__ bcur, uint* __restrict__ ebuf, int E) {
  __shared__ uint stage[PNBK][PCAP];
  __shared__ int lcnt[PNBK];
  int tid = threadIdx.x;
  if (tid < PNBK) lcnt[tid] = 0;
  __syncthreads();
  int e0 = blockIdx.x * PEPB;
  for (int r = 0; r < PEPB / 256; ++r) {
    int e = e0 + r * 256 + tid;
    if (e < E) {
      int d = dst[e], s = src[e];
      int b = d >> 11;
      uint pk = ((uint)s << 11) | (uint)(d & 2047);
      int pos = atomicAdd(&lcnt[b], 1);
      if (pos < PCAP) {
        stage[b][pos] = pk;
      } else {
        int p = atomicAdd(&bcur[b], 1);
        ebuf[p] = pk;
      }
    }
    if (r == 3 || r == PEPB / 256 - 1) {
      __syncthreads();
      if (tid < PNBK) {
        int c = lcnt[tid];
        if (c > PCAP) c = PCAP;
        if (c > 0) {
          int base = atomicAdd(&bcur[tid], c);
          for (int i = 0; i < c; ++i) ebuf[base + i] = stage[tid][i];
          lcnt[tid] = 0;
        }
      }
      __syncthreads();
    }
  }
}

// ---------------- per-bucket LDS counting sort (packed ebuf) ----------------
__global__ __launch_bounds__(1024)
void k_sort(const uint* __restrict__ ebuf, const int* __restrict__ bcur,
            int* __restrict__ rowbeg, int* __restrict__ rowend,
            int* __restrict__ csr, int N) {
  __shared__ int lcnt[2048];
  __shared__ int loff[2048];
  __shared__ int wsum[16];
  const int b = blockIdx.x;
  const int tid = threadIdx.x;
  const int lane = tid & 63, w = tid >> 6;
  const int base_e = b * ECAP;
  const int node0 = b << 11;
  const int ecnt = bcur[b] - base_e;

  lcnt[tid] = 0; lcnt[tid + 1024] = 0;
  __syncthreads();
  for (int i = tid; i < ecnt; i += 1024) {
    int dloc = (int)(ebuf[base_e + i] & 2047u);
    atomicAdd(&lcnt[dloc], 1);
  }
  __syncthreads();
  int v0 = lcnt[2 * tid], v1 = lcnt[2 * tid + 1];
  int s = v0 + v1;
  for (int off = 1; off < 64; off <<= 1) {
    int t = __shfl_up(s, off);
    if (lane >= off) s += t;
  }
  if (lane == 63) wsum[w] = s;
  __syncthreads();
  if (w == 0 && lane < 16) {
    int x = wsum[lane];
    int sx = x;
    for (int off = 1; off < 16; off <<= 1) {
      int t = __shfl_up(sx, off);
      if (lane >= off) sx += t;
    }
    wsum[lane] = sx - x;
  }
  __syncthreads();
  int excl = wsum[w] + (s - v0 - v1);
  loff[2 * tid] = excl;
  loff[2 * tid + 1] = excl + v0;
  __syncthreads();
  for (int i = tid; i < 2048; i += 1024) {
    int g = node0 + i;
    if (g < N) {
      int rb = base_e + loff[i];
      rowbeg[g] = rb;
      rowend[g] = rb + lcnt[i];
    }
    lcnt[i] = 0;
  }
  __syncthreads();
  for (int i = tid; i < ecnt; i += 1024) {
    uint p = ebuf[base_e + i];
    int dloc = (int)(p & 2047u);
    int pos = base_e + loff[dloc] + atomicAdd(&lcnt[dloc], 1);
    csr[pos] = (int)(p >> 11);
  }
}

// ---------------- fused GIN layer: fp8 gather (8-deep MLP), bf16 self/MLP ----------
__global__ __launch_bounds__(256, 8)
void k_layer(const ushort* __restrict__ H, const unsigned char* __restrict__ H8,
             const int* __restrict__ rowbeg, const int* __restrict__ rowend,
             const int* __restrict__ csr,
             const ushort* __restrict__ Wf1, const ushort* __restrict__ Wf2,
             const float* __restrict__ b1, const float* __restrict__ b2,
             const float* __restrict__ eps, int layer,
             ushort* __restrict__ Hout, unsigned char* __restrict__ H8out,
             const int* __restrict__ batch, float* __restrict__ pool,
             int col_off, int M, int write_next) {
  __shared__ uint Tz[1024];
  __shared__ uint Tt[1024];
  const int tid = threadIdx.x;
  const int w = tid >> 6, lane = tid & 63;
  const int m0 = blockIdx.x * 16;
  const float e = 1.0f + eps[layer];
  const uint* h32 = (const uint*)H;
  const ushort* h8 = (const ushort*)H8;   // 2 fp8 per ushort, 64 per row

  // ---- phase A: gather z rows (4 per wave), 8 loads in flight ----
  for (int r = 0; r < 4; ++r) {
    const int row = w * 4 + r;
    const int n = m0 + row;
    if (n < M) {
      uint u = h32[(size_t)n * 64 + lane];
      float a0 = bfu_lo(u) * e, a1 = bfu_hi(u) * e;   // self term, bf16
      float a2 = 0.f, a3 = 0.f;                        // second accumulator pair
      int s0 = rowbeg[n], s1 = rowend[n];
      for (int base = s0; base < s1; base += 64) {
        int cnt = s1 - base;
        if (cnt > 64) cnt = 64;
        int idx = (lane < cnt) ? csr[base + lane] : 0;
        int j = 0;
        for (; j + 8 <= cnt; j += 8) {
          int i0 = __shfl(idx, j),     i1 = __shfl(idx, j + 1);
          int i2 = __shfl(idx, j + 2), i3 = __shfl(idx, j + 3);
          int i4 = __shfl(idx, j + 4), i5 = __shfl(idx, j + 5);
          int i6 = __shfl(idx, j + 6), i7 = __shfl(idx, j + 7);
          uint u0 = h8[((uint)i0 << 6) | (uint)lane];
          uint u1 = h8[((uint)i1 << 6) | (uint)lane];
          uint u2 = h8[((uint)i2 << 6) | (uint)lane];
          uint u3 = h8[((uint)i3 << 6) | (uint)lane];
          uint u4 = h8[((uint)i4 << 6) | (uint)lane];
          uint u5 = h8[((uint)i5 << 6) | (uint)lane];
          uint u6 = h8[((uint)i6 << 6) | (uint)lane];
          uint u7 = h8[((uint)i7 << 6) | (uint)lane];
          float f0, f1;
          dec8(u0, f0, f1); a0 += f0; a1 += f1;
          dec8(u1, f0, f1); a0 += f0; a1 += f1;
          dec8(u2, f0, f1); a0 += f0; a1 += f1;
          dec8(u3, f0, f1); a0 += f0; a1 += f1;
          dec8(u4, f0, f1); a2 += f0; a3 += f1;
          dec8(u5, f0, f1); a2 += f0; a3 += f1;
          dec8(u6, f0, f1); a2 += f0; a3 += f1;
          dec8(u7, f0, f1); a2 += f0; a3 += f1;
        }
        for (; j + 4 <= cnt; j += 4) {
          int i0 = __shfl(idx, j),     i1 = __shfl(idx, j + 1);
          int i2 = __shfl(idx, j + 2), i3 = __shfl(idx, j + 3);
          uint u0 = h8[((uint)i0 << 6) | (uint)lane];
          uint u1 = h8[((uint)i1 << 6) | (uint)lane];
          uint u2 = h8[((uint)i2 << 6) | (uint)lane];
          uint u3 = h8[((uint)i3 << 6) | (uint)lane];
          float f0, f1;
          dec8(u0, f0, f1); a0 += f0; a1 += f1;
          dec8(u1, f0, f1); a0 += f0; a1 += f1;
          dec8(u2, f0, f1); a2 += f0; a3 += f1;
          dec8(u3, f0, f1); a2 += f0; a3 += f1;
        }
        for (; j < cnt; ++j) {
          int si = __shfl(idx, j);
          uint uu = h8[((uint)si << 6) | (uint)lane];
          float f0, f1;
          dec8(uu, f0, f1); a0 += f0; a1 += f1;
        }
      }
      a0 += a2; a1 += a3;
      Tz[row * 64 + (lane ^ ((row & 7) << 2))] = (uint)f2bf(a0) | ((uint)f2bf(a1) << 16);
    }
  }
  __syncthreads();

  // ---- phase B: GEMM1 (read Tz) -> relu -> Tt ----
  const int row16 = lane & 15, hi = lane >> 4;
  const int c2 = w << 1;
  const s16x8* wf1 = (const s16x8*)Wf1;
  f32x4 acc0 = (f32x4){0.f, 0.f, 0.f, 0.f};
  f32x4 acc1 = (f32x4){0.f, 0.f, 0.f, 0.f};
#pragma unroll
  for (int ks = 0; ks < 4; ++ks) {
    const s16x8 af = *(const s16x8*)(Tz + row16 * 64 + ((ks * 16 + hi * 4) ^ ((row16 & 7) << 2)));
    acc0 = __builtin_amdgcn_mfma_f32_16x16x32_bf16(af, wf1[((c2 + 0) * 4 + ks) * 64 + lane], acc0, 0, 0, 0);
    acc1 = __builtin_amdgcn_mfma_f32_16x16x32_bf16(af, wf1[((c2 + 1) * 4 + ks) * 64 + lane], acc1, 0, 0, 0);
  }
  {
    ushort* Tb = (ushort*)Tt;
    const float bb0 = b1[(c2 + 0) * 16 + row16];
    const float bb1 = b1[(c2 + 1) * 16 + row16];
#pragma unroll
    for (int i = 0; i < 4; ++i) {
      const int rr = hi * 4 + i;
      Tb[(rr * 128 + (c2 + 0) * 16 + row16) ^ ((rr & 7) << 3)] = f2bf(fmaxf(acc0[i] + bb0, 0.f));
      Tb[(rr * 128 + (c2 + 1) * 16 + row16) ^ ((rr & 7) << 3)] = f2bf(fmaxf(acc1[i] + bb1, 0.f));
    }
  }
  __syncthreads();

  // ---- phase C: GEMM2 (read Tt) + write bf16 + fp8 + pool ----
  const s16x8* wf2 = (const s16x8*)Wf2;
  f32x4 ac0 = (f32x4){0.f, 0.f, 0.f, 0.f};
  f32x4 ac1 = (f32x4){0.f, 0.f, 0.f, 0.f};
#pragma unroll
  for (int ks = 0; ks < 4; ++ks) {
    const s16x8 af = *(const s16x8*)(Tt + row16 * 64 + ((ks * 16 + hi * 4) ^ ((row16 & 7) << 2)));
    ac0 = __builtin_amdgcn_mfma_f32_16x16x32_bf16(af, wf2[((c2 + 0) * 4 + ks) * 64 + lane], ac0, 0, 0, 0);
    ac1 = __builtin_amdgcn_mfma_f32_16x16x32_bf16(af, wf2[((c2 + 1) * 4 + ks) * 64 + lane], ac1, 0, 0, 0);
  }
  {
    const int r0 = m0 + hi * 4;
    const int col0 = (c2 + 0) * 16 + row16, col1 = (c2 + 1) * 16 + row16;
    const float bb0 = b2[col0], bb1 = b2[col1];
    const bool full = (m0 + 15 < M);
    const int gf = batch[m0 < M ? m0 : (M - 1)];
    const int gl = batch[(m0 + 15) < M ? (m0 + 15) : (M - 1)];
    if (full && gf == gl) {
      float vs0 = 0.f, vs1 = 0.f;
#pragma unroll
      for (int i = 0; i < 4; ++i) {
        float v0 = ac0[i] + bb0, v1 = ac1[i] + bb1;
        if (write_next) {
          Hout[(size_t)(r0 + i) * 128 + col0] = f2bf(v0);
          Hout[(size_t)(r0 + i) * 128 + col1] = f2bf(v1);
          H8out[(size_t)(r0 + i) * 128 + col0] = (unsigned char)enc8(v0);
          H8out[(size_t)(r0 + i) * 128 + col1] = (unsigned char)enc8(v1);
        }
        vs0 += v0; vs1 += v1;
      }
      vs0 += __shfl_xor(vs0, 16); vs0 += __shfl_xor(vs0, 32);
      vs1 += __shfl_xor(vs1, 16); vs1 += __shfl_xor(vs1, 32);
      if (lane < 16) {
        atomicAdd(&pool[(size_t)gf * 384 + col_off + (c2 + 0) * 16 + lane], vs0);
        atomicAdd(&pool[(size_t)gf * 384 + col_off + (c2 + 1) * 16 + lane], vs1);
      }
    } else {
#pragma unroll
      for (int i = 0; i < 4; ++i) {
        const int rr = r0 + i;
        if (rr < M) {
          float v0 = ac0[i] + bb0, v1 = ac1[i] + bb1;
          if (write_next) {
            Hout[(size_t)rr * 128 + col0] = f2bf(v0);
            Hout[(size_t)rr * 128 + col1] = f2bf(v1);
            H8out[(size_t)rr * 128 + col0] = (unsigned char)enc8(v0);
            H8out[(size_t)rr * 128 + col1] = (unsigned char)enc8(v1);
          }
          int g = batch[rr];
          atomicAdd(&pool[(size_t)g * 384 + col_off + col0], v0);
          atomicAdd(&pool[(size_t)g * 384 + col_off + col1], v1);
        }
      }
    }
  }
}

// ---------------- fused pre-MLP: writes bf16 h0 and fp8 h0 ----------------
__global__ __launch_bounds__(256, 4)
void k_mlp2(const float* __restrict__ X, const ushort* __restrict__ Wf1,
            const ushort* __restrict__ Wf2, const float* __restrict__ b1,
            const float* __restrict__ b2, ushort* __restrict__ Hout,
            unsigned char* __restrict__ H8out, int M) {
  __shared__ uint lt[4][1024];
  const int lane = threadIdx.x & 63;
  const int wid = threadIdx.x >> 6;
  uint* T = lt[wid];
  const int m0 = blockIdx.x * 64 + wid * 16;
  if (m0 >= M) return;
  const int row = lane & 15, hi = lane >> 4;

  f32x4 acc[8];
#pragma unroll
  for (int nt = 0; nt < 8; ++nt) acc[nt] = (f32x4){0.f, 0.f, 0.f, 0.f};
  {
    const float* xrow = X + (size_t)(m0 + row) * 128;
    const s16x8* wf = (const s16x8*)Wf1;
#pragma unroll
    for (int ks = 0; ks < 4; ++ks) {
      float4 xa = *(const float4*)&xrow[ks * 32 + hi * 8];
      float4 xb = *(const float4*)&xrow[ks * 32 + hi * 8 + 4];
      s16x8 af;
      af[0] = (short)f2bf(xa.x); af[1] = (short)f2bf(xa.y);
      af[2] = (short)f2bf(xa.z); af[3] = (short)f2bf(xa.w);
      af[4] = (short)f2bf(xb.x); af[5] = (short)f2bf(xb.y);
      af[6] = (short)f2bf(xb.z); af[7] = (short)f2bf(xb.w);
#pragma unroll
      for (int nt = 0; nt < 8; ++nt)
        acc[nt] = __builtin_amdgcn_mfma_f32_16x16x32_bf16(af, wf[(nt * 4 + ks) * 64 + lane], acc[nt], 0, 0, 0);
    }
  }
  {
    ushort* Tb = (ushort*)T;
    const int r0l = hi * 4;
#pragma unroll
    for (int nt = 0; nt < 8; ++nt) {
      float bb = b1[nt * 16 + row];
      const int col = nt * 16 + row;
#pragma unroll
      for (int i = 0; i < 4; ++i) {
        int lr = r0l + i;
        float v = fmaxf(acc[nt][i] + bb, 0.f);
        Tb[(lr * 128 + col) ^ ((lr & 7) << 3)] = f2bf(v);
      }
    }
  }
#pragma unroll
  for (int nt = 0; nt < 8; ++nt) acc[nt] = (f32x4){0.f, 0.f, 0.f, 0.f};
  {
#pragma unroll
    for (int ks = 0; ks < 4; ++ks) {
      int ub = row * 64 + ((ks * 16 + hi * 4) ^ ((row & 7) << 2));
      s16x8 af = *(const s16x8*)(T + ub);
#pragma unroll
      for (int nt = 0; nt < 8; ++nt)
        acc[nt] = __builtin_amdgcn_mfma_f32_16x16x32_bf16(af, ((const s16x8*)Wf2)[(nt * 4 + ks) * 64 + lane], acc[nt], 0, 0, 0);
    }
  }
  {
    const int r0 = m0 + hi * 4;
#pragma unroll
    for (int nt = 0; nt < 8; ++nt) {
      const int col = nt * 16 + row;
      float bb = b2[col];
#pragma unroll
      for (int i = 0; i < 4; ++i) {
        float v = fmaxf(acc[nt][i] + bb, 0.f);
        Hout[(size_t)(r0 + i) * 128 + col] = f2bf(v);
        H8out[(size_t)(r0 + i) * 128 + col] = (unsigned char)enc8(v);
      }
    }
  }
}

extern "C" void kernel_launch(void* const* d_in, const int* in_sizes, int n_in,
                              void* d_out, int out_size, void* d_ws, size_t ws_size,
                              hipStream_t stream) {
  const float* x    = (const float*)d_in[0];
  const int*   ei   = (const int*)d_in[1];
  const int*   batch= (const int*)d_in[2];
  const float* Wp1  = (const float*)d_in[3];
  const float* bp1  = (const float*)d_in[4];
  const float* Wp2  = (const float*)d_in[5];
  const float* bp2  = (const float*)d_in[6];
  const float* W1s  = (const float*)d_in[7];
  const float* b1s  = (const float*)d_in[8];
  const float* W2s  = (const float*)d_in[9];
  const float* b2s  = (const float*)d_in[10];
  const float* eps  = (const float*)d_in[11];

  const int N = in_sizes[0] / 128;
  const int E = in_sizes[1] / 2;
  float* out = (float*)d_out;
  const int nbk = (N + 2047) >> 11;

  char* ws = (char*)d_ws;
  size_t off = 0;
  auto alloc = [&](size_t bytes) -> void* {
    void* p = ws + off;
    off += (bytes + 255) & ~(size_t)255;
    return p;
  };
  ushort* bufA  = (ushort*)alloc((size_t)N * 128 * 2);
  ushort* bufB  = (ushort*)alloc((size_t)N * 128 * 2);
  unsigned char* h8A = (unsigned char*)alloc((size_t)N * 128);
  unsigned char* h8B = (unsigned char*)alloc((size_t)N * 128);
  ushort* Wf    = (ushort*)alloc((size_t)8 * 16384 * 2);
  int* rowbeg   = (int*)alloc((size_t)N * 4);
  int* rowend   = (int*)alloc((size_t)N * 4);
  int* csr      = (int*)alloc((size_t)nbk * ECAP * 4);
  uint* ebuf    = (uint*)alloc((size_t)nbk * ECAP * 4);
  int* bcur     = (int*)alloc((size_t)(nbk + 1) * 4);
  (void)ws_size; (void)n_in;

  k_prepw<<<64, 256, 0, stream>>>(Wp1, Wp2, W1s, W2s, Wf, bcur, nbk, out, out_size);
  k_part<<<(E + PEPB - 1) / PEPB, 256, 0, stream>>>(ei, ei + E, bcur, ebuf, E);
  k_sort<<<nbk, 1024, 0, stream>>>(ebuf, bcur, rowbeg, rowend, csr, N);

  const int ngrid = (N + 63) / 64;
  k_mlp2<<<ngrid, 256, 0, stream>>>(x, Wf + 0 * 16384, Wf + 1 * 16384, bp1, bp2, bufA, h8A, N);

  const int lgrid = (N + 15) / 16;
  ushort* hin = bufA;
  ushort* hout = bufB;
  unsigned char* h8in = h8A;
  unsigned char* h8out = h8B;
  for (int L = 0; L < 3; ++L) {
    k_layer<<<lgrid, 256, 0, stream>>>(hin, h8in, rowbeg, rowend, csr,
                                       Wf + (2 + L) * 16384, Wf + (5 + L) * 16384,
                                       b1s + (size_t)L * 128, b2s + (size_t)L * 128,
                                       eps, L, hout, h8out, batch, out, L * 128, N,
                                       (L < 2) ? 1 : 0);
    ushort* tmp = hin; hin = hout; hout = tmp;
    unsigned char* t8 = h8in; h8in = h8out; h8out = t8;
  }
}

// Round 16
// 305.250 us; speedup vs baseline: 4.4493x; 1.0062x over previous
//
#include <hip/hip_runtime.h>

typedef float f32x2 __attribute__((ext_vector_type(2)));
typedef float f32x4 __attribute__((ext_vector_type(4)));
typedef short s16x8 __attribute__((ext_vector_type(8)));

#define ECAP 36864   // padded per-bucket edge capacity (mean 32768, +22 sigma)

#if __has_builtin(__builtin_amdgcn_cvt_pk_f32_fp8) && __has_builtin(__builtin_amdgcn_cvt_pk_fp8_f32)
#define HW_FP8 1
#else
#define HW_FP8 0
#endif

__device__ __forceinline__ ushort f2bf(float f) {
  uint u = __builtin_bit_cast(uint, f);
  u += 0x7fffu + ((u >> 16) & 1u);
  return (ushort)(u >> 16);
}
__device__ __forceinline__ float bfu_lo(uint u) { return __builtin_bit_cast(float, u << 16); }
__device__ __forceinline__ float bfu_hi(uint u) { return __builtin_bit_cast(float, u & 0xffff0000u); }

// f32 -> fp8 byte (HW OCP e4m3fn if available, else custom e4m3-style)
__device__ __forceinline__ uint enc8(float f) {
#if HW_FP8
  return (uint)(__builtin_amdgcn_cvt_pk_fp8_f32(f, f, 0, false) & 0xff);
#else
  uint u = __builtin_bit_cast(uint, f);
  uint s = (u >> 24) & 0x80u;
  uint a = u & 0x7fffffffu;
  uint r = a + 0x7ffffu + ((a >> 20) & 1u);
  int em = (int)(r >> 20) - 960;
  em = em < 0 ? 0 : (em > 126 ? 126 : em);
  return s | (uint)em;
#endif
}
// decode 2 packed fp8 (lo byte = even col, hi byte = odd col) -> 2 f32
__device__ __forceinline__ void dec8(uint u, float& f0, float& f1) {
#if HW_FP8
  f32x2 r = __builtin_amdgcn_cvt_pk_f32_fp8((int)u, false);
  f0 = r.x; f1 = r.y;
#else
  uint v = u | (u << 8);
  uint p = (((v & 0x007f007fu) << 4) + 0x3C003C00u) | ((v & 0x00800080u) << 8);
  f0 = __builtin_bit_cast(float, p << 16);
  f1 = __builtin_bit_cast(float, p & 0xffff0000u);
#endif
}

// ---------------- reformat 8 weight matrices into MFMA B-fragment order ----------------
// also initializes bcur and zeroes the pool output
__global__ void k_prepw(const float* __restrict__ Wp1, const float* __restrict__ Wp2,
                        const float* __restrict__ W1s, const float* __restrict__ W2s,
                        ushort* __restrict__ Wf, int* __restrict__ bcur, int nbk,
                        float* __restrict__ out, int out_size) {
  int t = blockIdx.x * blockDim.x + threadIdx.x;
  if (t <= nbk) bcur[t] = t * ECAP;
  for (int i = t; i < out_size; i += 16384) out[i] = 0.f;
  if (t >= 8 * 2048) return;
  int m = t >> 11;
  int r = t & 2047;
  int lane = r & 63;
  int ksnt = r >> 6;
  int ks = ksnt & 3;
  int nt = ksnt >> 2;
  const float* src = (m == 0) ? Wp1 : (m == 1) ? Wp2
                     : (m < 5) ? (W1s + (size_t)(m - 2) * 16384)
                               : (W2s + (size_t)(m - 5) * 16384);
  ushort* dst = Wf + (size_t)m * 16384 + (size_t)r * 8;
  int c = nt * 16 + (lane & 15);
  int kbase = ks * 32 + (lane >> 4) * 8;
  for (int i = 0; i < 8; ++i) dst[i] = f2bf(src[(size_t)(kbase + i) * 128 + c]);
}

// ---------------- LDS-staged multi-split (packed records) ----------------
#define PNBK 64
#define PCAP 128
#define PEPB 2048
__global__ __launch_bounds__(256)
void k_part(const int* __restrict__ src, const int* __restrict__ dst,
            int* __restrict__ bcur, uint* __restrict__ ebuf, int E) {
  __shared__ uint stage[PNBK][PCAP];
  __shared__ int lcnt[PNBK];
  int tid = threadIdx.x;
  if (tid < PNBK) lcnt[tid] = 0;
  __syncthreads();
  int e0 = blockIdx.x * PEPB;
  for (int r = 0; r < PEPB / 256; ++r) {
    int e = e0 + r * 256 + tid;
    if (e < E) {
      int d = dst[e], s = src[e];
      int b = d >> 11;
      uint pk = ((uint)s << 11) | (uint)(d & 2047);
      int pos = atomicAdd(&lcnt[b], 1);
      if (pos < PCAP) {
        stage[b][pos] = pk;
      } else {
        int p = atomicAdd(&bcur[b], 1);
        ebuf[p] = pk;
      }
    }
    if (r == 3 || r == PEPB / 256 - 1) {
      __syncthreads();
      if (tid < PNBK) {
        int c = lcnt[tid];
        if (c > PCAP) c = PCAP;
        if (c > 0) {
          int base = atomicAdd(&bcur[tid], c);
          for (int i = 0; i < c; ++i) ebuf[base + i] = stage[tid][i];
          lcnt[tid] = 0;
        }
      }
      __syncthreads();
    }
  }
}

// ---------------- per-bucket LDS counting sort (packed ebuf) ----------------
__global__ __launch_bounds__(1024)
void k_sort(const uint* __restrict__ ebuf, const int* __restrict__ bcur,
            int* __restrict__ rowbeg, int* __restrict__ rowend,
            int* __restrict__ csr, int N) {
  __shared__ int lcnt[2048];
  __shared__ int loff[2048];
  __shared__ int wsum[16];
  const int b = blockIdx.x;
  const int tid = threadIdx.x;
  const int lane = tid & 63, w = tid >> 6;
  const int base_e = b * ECAP;
  const int node0 = b << 11;
  const int ecnt = bcur[b] - base_e;

  lcnt[tid] = 0; lcnt[tid + 1024] = 0;
  __syncthreads();
  for (int i = tid; i < ecnt; i += 1024) {
    int dloc = (int)(ebuf[base_e + i] & 2047u);
    atomicAdd(&lcnt[dloc], 1);
  }
  __syncthreads();
  int v0 = lcnt[2 * tid], v1 = lcnt[2 * tid + 1];
  int s = v0 + v1;
  for (int off = 1; off < 64; off <<= 1) {
    int t = __shfl_up(s, off);
    if (lane >= off) s += t;
  }
  if (lane == 63) wsum[w] = s;
  __syncthreads();
  if (w == 0 && lane < 16) {
    int x = wsum[lane];
    int sx = x;
    for (int off = 1; off < 16; off <<= 1) {
      int t = __shfl_up(sx, off);
      if (lane >= off) sx += t;
    }
    wsum[lane] = sx - x;
  }
  __syncthreads();
  int excl = wsum[w] + (s - v0 - v1);
  loff[2 * tid] = excl;
  loff[2 * tid + 1] = excl + v0;
  __syncthreads();
  for (int i = tid; i < 2048; i += 1024) {
    int g = node0 + i;
    if (g < N) {
      int rb = base_e + loff[i];
      rowbeg[g] = rb;
      rowend[g] = rb + lcnt[i];
    }
    lcnt[i] = 0;
  }
  __syncthreads();
  for (int i = tid; i < ecnt; i += 1024) {
    uint p = ebuf[base_e + i];
    int dloc = (int)(p & 2047u);
    int pos = base_e + loff[dloc] + atomicAdd(&lcnt[dloc], 1);
    csr[pos] = (int)(p >> 11);
  }
}

// ---------------- fused GIN layer: fp8 gather, row-pair jam (16 loads in flight) --------
__global__ __launch_bounds__(256, 6)
void k_layer(const ushort* __restrict__ H, const unsigned char* __restrict__ H8,
             const int* __restrict__ rowbeg, const int* __restrict__ rowend,
             const int* __restrict__ csr,
             const ushort* __restrict__ Wf1, const ushort* __restrict__ Wf2,
             const float* __restrict__ b1, const float* __restrict__ b2,
             const float* __restrict__ eps, int layer,
             ushort* __restrict__ Hout, unsigned char* __restrict__ H8out,
             const int* __restrict__ batch, float* __restrict__ pool,
             int col_off, int M, int write_next) {
  __shared__ uint Tz[1024];
  __shared__ uint Tt[1024];
  const int tid = threadIdx.x;
  const int w = tid >> 6, lane = tid & 63;
  const int m0 = blockIdx.x * 16;
  const float e = 1.0f + eps[layer];
  const uint* h32 = (const uint*)H;
  const ushort* h8 = (const ushort*)H8;   // 2 fp8 per ushort, 64 per row

  // ---- phase A: gather row-pairs; A and B chains give up to 16 loads in flight ----
  for (int rp = 0; rp < 2; ++rp) {
    const int rowA = w * 4 + rp * 2, rowB = rowA + 1;
    const int nA = m0 + rowA, nB = m0 + rowB;
    const bool vA = nA < M, vB = nB < M;
    float a0 = 0.f, a1 = 0.f, a2 = 0.f, a3 = 0.f;
    float b0v = 0.f, b1v = 0.f, b2v = 0.f, b3v = 0.f;
    if (vA) { uint u = h32[(size_t)nA * 64 + lane]; a0 = bfu_lo(u) * e; a1 = bfu_hi(u) * e; }
    if (vB) { uint u = h32[(size_t)nB * 64 + lane]; b0v = bfu_lo(u) * e; b1v = bfu_hi(u) * e; }
    int sA = vA ? rowbeg[nA] : 0, eA = vA ? rowend[nA] : 0;
    int sB = vB ? rowbeg[nB] : 0, eB = vB ? rowend[nB] : 0;
    while (sA < eA || sB < eB) {
      int cntA = eA - sA; cntA = cntA < 0 ? 0 : (cntA > 64 ? 64 : cntA);
      int cntB = eB - sB; cntB = cntB < 0 ? 0 : (cntB > 64 ? 64 : cntB);
      int idxA = (lane < cntA) ? csr[sA + lane] : 0;
      int idxB = (lane < cntB) ? csr[sB + lane] : 0;
      int jA = 0, jB = 0;
      // joint phase: 8 A + 8 B loads issued before any decode (16 in flight)
      while (jA + 8 <= cntA && jB + 8 <= cntB) {
        int iA0 = __shfl(idxA, jA),     iA1 = __shfl(idxA, jA + 1);
        int iA2 = __shfl(idxA, jA + 2), iA3 = __shfl(idxA, jA + 3);
        int iA4 = __shfl(idxA, jA + 4), iA5 = __shfl(idxA, jA + 5);
        int iA6 = __shfl(idxA, jA + 6), iA7 = __shfl(idxA, jA + 7);
        int iB0 = __shfl(idxB, jB),     iB1 = __shfl(idxB, jB + 1);
        int iB2 = __shfl(idxB, jB + 2), iB3 = __shfl(idxB, jB + 3);
        int iB4 = __shfl(idxB, jB + 4), iB5 = __shfl(idxB, jB + 5);
        int iB6 = __shfl(idxB, jB + 6), iB7 = __shfl(idxB, jB + 7);
        uint uA0 = h8[((uint)iA0 << 6) | (uint)lane];
        uint uA1 = h8[((uint)iA1 << 6) | (uint)lane];
        uint uA2 = h8[((uint)iA2 << 6) | (uint)lane];
        uint uA3 = h8[((uint)iA3 << 6) | (uint)lane];
        uint uA4 = h8[((uint)iA4 << 6) | (uint)lane];
        uint uA5 = h8[((uint)iA5 << 6) | (uint)lane];
        uint uA6 = h8[((uint)iA6 << 6) | (uint)lane];
        uint uA7 = h8[((uint)iA7 << 6) | (uint)lane];
        uint uB0 = h8[((uint)iB0 << 6) | (uint)lane];
        uint uB1 = h8[((uint)iB1 << 6) | (uint)lane];
        uint uB2 = h8[((uint)iB2 << 6) | (uint)lane];
        uint uB3 = h8[((uint)iB3 << 6) | (uint)lane];
        uint uB4 = h8[((uint)iB4 << 6) | (uint)lane];
        uint uB5 = h8[((uint)iB5 << 6) | (uint)lane];
        uint uB6 = h8[((uint)iB6 << 6) | (uint)lane];
        uint uB7 = h8[((uint)iB7 << 6) | (uint)lane];
        float f0, f1;
        dec8(uA0, f0, f1); a0 += f0; a1 += f1;
        dec8(uA1, f0, f1); a0 += f0; a1 += f1;
        dec8(uA2, f0, f1); a0 += f0; a1 += f1;
        dec8(uA3, f0, f1); a0 += f0; a1 += f1;
        dec8(uA4, f0, f1); a2 += f0; a3 += f1;
        dec8(uA5, f0, f1); a2 += f0; a3 += f1;
        dec8(uA6, f0, f1); a2 += f0; a3 += f1;
        dec8(uA7, f0, f1); a2 += f0; a3 += f1;
        dec8(uB0, f0, f1); b0v += f0; b1v += f1;
        dec8(uB1, f0, f1); b0v += f0; b1v += f1;
        dec8(uB2, f0, f1); b0v += f0; b1v += f1;
        dec8(uB3, f0, f1); b0v += f0; b1v += f1;
        dec8(uB4, f0, f1); b2v += f0; b3v += f1;
        dec8(uB5, f0, f1); b2v += f0; b3v += f1;
        dec8(uB6, f0, f1); b2v += f0; b3v += f1;
        dec8(uB7, f0, f1); b2v += f0; b3v += f1;
        jA += 8; jB += 8;
      }
      // A-only 8-deep
      while (jA + 8 <= cntA) {
        int i0 = __shfl(idxA, jA),     i1 = __shfl(idxA, jA + 1);
        int i2 = __shfl(idxA, jA + 2), i3 = __shfl(idxA, jA + 3);
        int i4 = __shfl(idxA, jA + 4), i5 = __shfl(idxA, jA + 5);
        int i6 = __shfl(idxA, jA + 6), i7 = __shfl(idxA, jA + 7);
        uint u0 = h8[((uint)i0 << 6) | (uint)lane];
        uint u1 = h8[((uint)i1 << 6) | (uint)lane];
        uint u2 = h8[((uint)i2 << 6) | (uint)lane];
        uint u3 = h8[((uint)i3 << 6) | (uint)lane];
        uint u4 = h8[((uint)i4 << 6) | (uint)lane];
        uint u5 = h8[((uint)i5 << 6) | (uint)lane];
        uint u6 = h8[((uint)i6 << 6) | (uint)lane];
        uint u7 = h8[((uint)i7 << 6) | (uint)lane];
        float f0, f1;
        dec8(u0, f0, f1); a0 += f0; a1 += f1;
        dec8(u1, f0, f1); a0 += f0; a1 += f1;
        dec8(u2, f0, f1); a0 += f0; a1 += f1;
        dec8(u3, f0, f1); a0 += f0; a1 += f1;
        dec8(u4, f0, f1); a2 += f0; a3 += f1;
        dec8(u5, f0, f1); a2 += f0; a3 += f1;
        dec8(u6, f0, f1); a2 += f0; a3 += f1;
        dec8(u7, f0, f1); a2 += f0; a3 += f1;
        jA += 8;
      }
      // B-only 8-deep
      while (jB + 8 <= cntB) {
        int i0 = __shfl(idxB, jB),     i1 = __shfl(idxB, jB + 1);
        int i2 = __shfl(idxB, jB + 2), i3 = __shfl(idxB, jB + 3);
        int i4 = __shfl(idxB, jB + 4), i5 = __shfl(idxB, jB + 5);
        int i6 = __shfl(idxB, jB + 6), i7 = __shfl(idxB, jB + 7);
        uint u0 = h8[((uint)i0 << 6) | (uint)lane];
        uint u1 = h8[((uint)i1 << 6) | (uint)lane];
        uint u2 = h8[((uint)i2 << 6) | (uint)lane];
        uint u3 = h8[((uint)i3 << 6) | (uint)lane];
        uint u4 = h8[((uint)i4 << 6) | (uint)lane];
        uint u5 = h8[((uint)i5 << 6) | (uint)lane];
        uint u6 = h8[((uint)i6 << 6) | (uint)lane];
        uint u7 = h8[((uint)i7 << 6) | (uint)lane];
        float f0, f1;
        dec8(u0, f0, f1); b0v += f0; b1v += f1;
        dec8(u1, f0, f1); b0v += f0; b1v += f1;
        dec8(u2, f0, f1); b0v += f0; b1v += f1;
        dec8(u3, f0, f1); b0v += f0; b1v += f1;
        dec8(u4, f0, f1); b2v += f0; b3v += f1;
        dec8(u5, f0, f1); b2v += f0; b3v += f1;
        dec8(u6, f0, f1); b2v += f0; b3v += f1;
        dec8(u7, f0, f1); b2v += f0; b3v += f1;
        jB += 8;
      }
      // joint 4+4
      if (jA + 4 <= cntA && jB + 4 <= cntB) {
        int iA0 = __shfl(idxA, jA),     iA1 = __shfl(idxA, jA + 1);
        int iA2 = __shfl(idxA, jA + 2), iA3 = __shfl(idxA, jA + 3);
        int iB0 = __shfl(idxB, jB),     iB1 = __shfl(idxB, jB + 1);
        int iB2 = __shfl(idxB, jB + 2), iB3 = __shfl(idxB, jB + 3);
        uint uA0 = h8[((uint)iA0 << 6) | (uint)lane];
        uint uA1 = h8[((uint)iA1 << 6) | (uint)lane];
        uint uA2 = h8[((uint)iA2 << 6) | (uint)lane];
        uint uA3 = h8[((uint)iA3 << 6) | (uint)lane];
        uint uB0 = h8[((uint)iB0 << 6) | (uint)lane];
        uint uB1 = h8[((uint)iB1 << 6) | (uint)lane];
        uint uB2 = h8[((uint)iB2 << 6) | (uint)lane];
        uint uB3 = h8[((uint)iB3 << 6) | (uint)lane];
        float f0, f1;
        dec8(uA0, f0, f1); a0 += f0; a1 += f1;
        dec8(uA1, f0, f1); a0 += f0; a1 += f1;
        dec8(uA2, f0, f1); a2 += f0; a3 += f1;
        dec8(uA3, f0, f1); a2 += f0; a3 += f1;
        dec8(uB0, f0, f1); b0v += f0; b1v += f1;
        dec8(uB1, f0, f1); b0v += f0; b1v += f1;
        dec8(uB2, f0, f1); b2v += f0; b3v += f1;
        dec8(uB3, f0, f1); b2v += f0; b3v += f1;
        jA += 4; jB += 4;
      }
      while (jA + 4 <= cntA) {
        int i0 = __shfl(idxA, jA),     i1 = __shfl(idxA, jA + 1);
        int i2 = __shfl(idxA, jA + 2), i3 = __shfl(idxA, jA + 3);
        uint u0 = h8[((uint)i0 << 6) | (uint)lane];
        uint u1 = h8[((uint)i1 << 6) | (uint)lane];
        uint u2 = h8[((uint)i2 << 6) | (uint)lane];
        uint u3 = h8[((uint)i3 << 6) | (uint)lane];
        float f0, f1;
        dec8(u0, f0, f1); a0 += f0; a1 += f1;
        dec8(u1, f0, f1); a0 += f0; a1 += f1;
        dec8(u2, f0, f1); a2 += f0; a3 += f1;
        dec8(u3, f0, f1); a2 += f0; a3 += f1;
        jA += 4;
      }
      while (jB + 4 <= cntB) {
        int i0 = __shfl(idxB, jB),     i1 = __shfl(idxB, jB + 1);
        int i2 = __shfl(idxB, jB + 2), i3 = __shfl(idxB, jB + 3);
        uint u0 = h8[((uint)i0 << 6) | (uint)lane];
        uint u1 = h8[((uint)i1 << 6) | (uint)lane];
        uint u2 = h8[((uint)i2 << 6) | (uint)lane];
        uint u3 = h8[((uint)i3 << 6) | (uint)lane];
        float f0, f1;
        dec8(u0, f0, f1); b0v += f0; b1v += f1;
        dec8(u1, f0, f1); b0v += f0; b1v += f1;
        dec8(u2, f0, f1); b2v += f0; b3v += f1;
        dec8(u3, f0, f1); b2v += f0; b3v += f1;
        jB += 4;
      }
      for (; jA < cntA; ++jA) {
        int si = __shfl(idxA, jA);
        uint uu = h8[((uint)si << 6) | (uint)lane];
        float f0, f1;
        dec8(uu, f0, f1); a0 += f0; a1 += f1;
      }
      for (; jB < cntB; ++jB) {
        int si = __shfl(idxB, jB);
        uint uu = h8[((uint)si << 6) | (uint)lane];
        float f0, f1;
        dec8(uu, f0, f1); b0v += f0; b1v += f1;
      }
      sA += cntA; sB += cntB;
    }
    a0 += a2; a1 += a3; b0v += b2v; b1v += b3v;
    if (vA) Tz[rowA * 64 + (lane ^ ((rowA & 7) << 2))] = (uint)f2bf(a0) | ((uint)f2bf(a1) << 16);
    if (vB) Tz[rowB * 64 + (lane ^ ((rowB & 7) << 2))] = (uint)f2bf(b0v) | ((uint)f2bf(b1v) << 16);
  }
  __syncthreads();

  // ---- phase B: GEMM1 (read Tz) -> relu -> Tt ----
  const int row16 = lane & 15, hi = lane >> 4;
  const int c2 = w << 1;
  const s16x8* wf1 = (const s16x8*)Wf1;
  f32x4 acc0 = (f32x4){0.f, 0.f, 0.f, 0.f};
  f32x4 acc1 = (f32x4){0.f, 0.f, 0.f, 0.f};
#pragma unroll
  for (int ks = 0; ks < 4; ++ks) {
    const s16x8 af = *(const s16x8*)(Tz + row16 * 64 + ((ks * 16 + hi * 4) ^ ((row16 & 7) << 2)));
    acc0 = __builtin_amdgcn_mfma_f32_16x16x32_bf16(af, wf1[((c2 + 0) * 4 + ks) * 64 + lane], acc0, 0, 0, 0);
    acc1 = __builtin_amdgcn_mfma_f32_16x16x32_bf16(af, wf1[((c2 + 1) * 4 + ks) * 64 + lane], acc1, 0, 0, 0);
  }
  {
    ushort* Tb = (ushort*)Tt;
    const float bb0 = b1[(c2 + 0) * 16 + row16];
    const float bb1 = b1[(c2 + 1) * 16 + row16];
#pragma unroll
    for (int i = 0; i < 4; ++i) {
      const int rr = hi * 4 + i;
      Tb[(rr * 128 + (c2 + 0) * 16 + row16) ^ ((rr & 7) << 3)] = f2bf(fmaxf(acc0[i] + bb0, 0.f));
      Tb[(rr * 128 + (c2 + 1) * 16 + row16) ^ ((rr & 7) << 3)] = f2bf(fmaxf(acc1[i] + bb1, 0.f));
    }
  }
  __syncthreads();

  // ---- phase C: GEMM2 (read Tt) + write bf16 + fp8 + pool ----
  const s16x8* wf2 = (const s16x8*)Wf2;
  f32x4 ac0 = (f32x4){0.f, 0.f, 0.f, 0.f};
  f32x4 ac1 = (f32x4){0.f, 0.f, 0.f, 0.f};
#pragma unroll
  for (int ks = 0; ks < 4; ++ks) {
    const s16x8 af = *(const s16x8*)(Tt + row16 * 64 + ((ks * 16 + hi * 4) ^ ((row16 & 7) << 2)));
    ac0 = __builtin_amdgcn_mfma_f32_16x16x32_bf16(af, wf2[((c2 + 0) * 4 + ks) * 64 + lane], ac0, 0, 0, 0);
    ac1 = __builtin_amdgcn_mfma_f32_16x16x32_bf16(af, wf2[((c2 + 1) * 4 + ks) * 64 + lane], ac1, 0, 0, 0);
  }
  {
    const int r0 = m0 + hi * 4;
    const int col0 = (c2 + 0) * 16 + row16, col1 = (c2 + 1) * 16 + row16;
    const float bb0 = b2[col0], bb1 = b2[col1];
    const bool full = (m0 + 15 < M);
    const int gf = batch[m0 < M ? m0 : (M - 1)];
    const int gl = batch[(m0 + 15) < M ? (m0 + 15) : (M - 1)];
    if (full && gf == gl) {
      float vs0 = 0.f, vs1 = 0.f;
#pragma unroll
      for (int i = 0; i < 4; ++i) {
        float v0 = ac0[i] + bb0, v1 = ac1[i] + bb1;
        if (write_next) {
          Hout[(size_t)(r0 + i) * 128 + col0] = f2bf(v0);
          Hout[(size_t)(r0 + i) * 128 + col1] = f2bf(v1);
          H8out[(size_t)(r0 + i) * 128 + col0] = (unsigned char)enc8(v0);
          H8out[(size_t)(r0 + i) * 128 + col1] = (unsigned char)enc8(v1);
        }
        vs0 += v0; vs1 += v1;
      }
      vs0 += __shfl_xor(vs0, 16); vs0 += __shfl_xor(vs0, 32);
      vs1 += __shfl_xor(vs1, 16); vs1 += __shfl_xor(vs1, 32);
      if (lane < 16) {
        atomicAdd(&pool[(size_t)gf * 384 + col_off + (c2 + 0) * 16 + lane], vs0);
        atomicAdd(&pool[(size_t)gf * 384 + col_off + (c2 + 1) * 16 + lane], vs1);
      }
    } else {
#pragma unroll
      for (int i = 0; i < 4; ++i) {
        const int rr = r0 + i;
        if (rr < M) {
          float v0 = ac0[i] + bb0, v1 = ac1[i] + bb1;
          if (write_next) {
            Hout[(size_t)rr * 128 + col0] = f2bf(v0);
            Hout[(size_t)rr * 128 + col1] = f2bf(v1);
            H8out[(size_t)rr * 128 + col0] = (unsigned char)enc8(v0);
            H8out[(size_t)rr * 128 + col1] = (unsigned char)enc8(v1);
          }
          int g = batch[rr];
          atomicAdd(&pool[(size_t)g * 384 + col_off + col0], v0);
          atomicAdd(&pool[(size_t)g * 384 + col_off + col1], v1);
        }
      }
    }
  }
}

// ---------------- fused pre-MLP: writes bf16 h0 and fp8 h0 ----------------
__global__ __launch_bounds__(256, 4)
void k_mlp2(const float* __restrict__ X, const ushort* __restrict__ Wf1,
            const ushort* __restrict__ Wf2, const float* __restrict__ b1,
            const float* __restrict__ b2, ushort* __restrict__ Hout,
            unsigned char* __restrict__ H8out, int M) {
  __shared__ uint lt[4][1024];
  const int lane = threadIdx.x & 63;
  const int wid = threadIdx.x >> 6;
  uint* T = lt[wid];
  const int m0 = blockIdx.x * 64 + wid * 16;
  if (m0 >= M) return;
  const int row = lane & 15, hi = lane >> 4;

  f32x4 acc[8];
#pragma unroll
  for (int nt = 0; nt < 8; ++nt) acc[nt] = (f32x4){0.f, 0.f, 0.f, 0.f};
  {
    const float* xrow = X + (size_t)(m0 + row) * 128;
    const s16x8* wf = (const s16x8*)Wf1;
#pragma unroll
    for (int ks = 0; ks < 4; ++ks) {
      float4 xa = *(const float4*)&xrow[ks * 32 + hi * 8];
      float4 xb = *(const float4*)&xrow[ks * 32 + hi * 8 + 4];
      s16x8 af;
      af[0] = (short)f2bf(xa.x); af[1] = (short)f2bf(xa.y);
      af[2] = (short)f2bf(xa.z); af[3] = (short)f2bf(xa.w);
      af[4] = (short)f2bf(xb.x); af[5] = (short)f2bf(xb.y);
      af[6] = (short)f2bf(xb.z); af[7] = (short)f2bf(xb.w);
#pragma unroll
      for (int nt = 0; nt < 8; ++nt)
        acc[nt] = __builtin_amdgcn_mfma_f32_16x16x32_bf16(af, wf[(nt * 4 + ks) * 64 + lane], acc[nt], 0, 0, 0);
    }
  }
  {
    ushort* Tb = (ushort*)T;
    const int r0l = hi * 4;
#pragma unroll
    for (int nt = 0; nt < 8; ++nt) {
      float bb = b1[nt * 16 + row];
      const int col = nt * 16 + row;
#pragma unroll
      for (int i = 0; i < 4; ++i) {
        int lr = r0l + i;
        float v = fmaxf(acc[nt][i] + bb, 0.f);
        Tb[(lr * 128 + col) ^ ((lr & 7) << 3)] = f2bf(v);
      }
    }
  }
#pragma unroll
  for (int nt = 0; nt < 8; ++nt) acc[nt] = (f32x4){0.f, 0.f, 0.f, 0.f};
  {
#pragma unroll
    for (int ks = 0; ks < 4; ++ks) {
      int ub = row * 64 + ((ks * 16 + hi * 4) ^ ((row & 7) << 2));
      s16x8 af = *(const s16x8*)(T + ub);
#pragma unroll
      for (int nt = 0; nt < 8; ++nt)
        acc[nt] = __builtin_amdgcn_mfma_f32_16x16x32_bf16(af, ((const s16x8*)Wf2)[(nt * 4 + ks) * 64 + lane], acc[nt], 0, 0, 0);
    }
  }
  {
    const int r0 = m0 + hi * 4;
#pragma unroll
    for (int nt = 0; nt < 8; ++nt) {
      const int col = nt * 16 + row;
      float bb = b2[col];
#pragma unroll
      for (int i = 0; i < 4; ++i) {
        float v = fmaxf(acc[nt][i] + bb, 0.f);
        Hout[(size_t)(r0 + i) * 128 + col] = f2bf(v);
        H8out[(size_t)(r0 + i) * 128 + col] = (unsigned char)enc8(v);
      }
    }
  }
}

extern "C" void kernel_launch(void* const* d_in, const int* in_sizes, int n_in,
                              void* d_out, int out_size, void* d_ws, size_t ws_size,
                              hipStream_t stream) {
  const float* x    = (const float*)d_in[0];
  const int*   ei   = (const int*)d_in[1];
  const int*   batch= (const int*)d_in[2];
  const float* Wp1  = (const float*)d_in[3];
  const float* bp1  = (const float*)d_in[4];
  const float* Wp2  = (const float*)d_in[5];
  const float* bp2  = (const float*)d_in[6];
  const float* W1s  = (const float*)d_in[7];
  const float* b1s  = (const float*)d_in[8];
  const float* W2s  = (const float*)d_in[9];
  const float* b2s  = (const float*)d_in[10];
  const float* eps  = (const float*)d_in[11];

  const int N = in_sizes[0] / 128;
  const int E = in_sizes[1] / 2;
  float* out = (float*)d_out;
  const int nbk = (N + 2047) >> 11;

  char* ws = (char*)d_ws;
  size_t off = 0;
  auto alloc = [&](size_t bytes) -> void* {
    void* p = ws + off;
    off += (bytes + 255) & ~(size_t)255;
    return p;
  };
  ushort* bufA  = (ushort*)alloc((size_t)N * 128 * 2);
  ushort* bufB  = (ushort*)alloc((size_t)N * 128 * 2);
  unsigned char* h8A = (unsigned char*)alloc((size_t)N * 128);
  unsigned char* h8B = (unsigned char*)alloc((size_t)N * 128);
  ushort* Wf    = (ushort*)alloc((size_t)8 * 16384 * 2);
  int* rowbeg   = (int*)alloc((size_t)N * 4);
  int* rowend   = (int*)alloc((size_t)N * 4);
  int* csr      = (int*)alloc((size_t)nbk * ECAP * 4);
  uint* ebuf    = (uint*)alloc((size_t)nbk * ECAP * 4);
  int* bcur     = (int*)alloc((size_t)(nbk + 1) * 4);
  (void)ws_size; (void)n_in;

  k_prepw<<<64, 256, 0, stream>>>(Wp1, Wp2, W1s, W2s, Wf, bcur, nbk, out, out_size);
  k_part<<<(E + PEPB - 1) / PEPB, 256, 0, stream>>>(ei, ei + E, bcur, ebuf, E);
  k_sort<<<nbk, 1024, 0, stream>>>(ebuf, bcur, rowbeg, rowend, csr, N);

  const int ngrid = (N + 63) / 64;
  k_mlp2<<<ngrid, 256, 0, stream>>>(x, Wf + 0 * 16384, Wf + 1 * 16384, bp1, bp2, bufA, h8A, N);

  const int lgrid = (N + 15) / 16;
  ushort* hin = bufA;
  ushort* hout = bufB;
  unsigned char* h8in = h8A;
  unsigned char* h8out = h8B;
  for (int L = 0; L < 3; ++L) {
    k_layer<<<lgrid, 256, 0, stream>>>(hin, h8in, rowbeg, rowend, csr,
                                       Wf + (2 + L) * 16384, Wf + (5 + L) * 16384,
                                       b1s + (size_t)L * 128, b2s + (size_t)L * 128,
                                       eps, L, hout, h8out, batch, out, L * 128, N,
                                       (L < 2) ? 1 : 0);
    ushort* tmp = hin; hin = hout; hout = tmp;
    unsigned char* t8 = h8in; h8in = h8out; h8out = t8;
  }
}